// Round 11
// baseline (140.823 us; speedup 1.0000x reference)
//
#include <hip/hip_runtime.h>
#include <hip/hip_bf16.h>

// Problem constants (fixed by setup_inputs): B=4, S=2048, H=16, DH=64, W=4,
// Kc=512, D=1024. Output (4,2048,1024) f32.

typedef __attribute__((ext_vector_type(8))) short short8;   // 8 bf16 (4 VGPRs)
typedef __attribute__((ext_vector_type(4))) short short4v;  // 4 bf16 (2 VGPRs)
typedef __attribute__((ext_vector_type(4))) float f32x4;
typedef __attribute__((ext_vector_type(4))) int int4e;
typedef __attribute__((ext_vector_type(2))) unsigned int u32x2;

#define MFMA32(A, Bf, C) __builtin_amdgcn_mfma_f32_16x16x32_bf16((A), (Bf), (C), 0, 0, 0)
#define MFMA16(A, Bf, C) __builtin_amdgcn_mfma_f32_16x16x16bf16_1k((A), (Bf), (C), 0, 0, 0)

static __device__ __forceinline__ unsigned short f2bf(float f) {
  unsigned int u = __builtin_bit_cast(unsigned int, f);
  u += 0x7fffu + ((u >> 16) & 1u);   // RNE (finite inputs only)
  return (unsigned short)(u >> 16);
}
static __device__ __forceinline__ unsigned int pack2c(float a, float b) {
  unsigned short lo = __builtin_bit_cast(unsigned short, __float2bfloat16(a));
  unsigned short hi = __builtin_bit_cast(unsigned short, __float2bfloat16(b));
  return (unsigned int)lo | ((unsigned int)hi << 16);
}
static __device__ __forceinline__ short4v pk4(float a, float b, float c, float d) {
  short4v r;
  r[0] = (short)__builtin_bit_cast(unsigned short, __float2bfloat16(a));
  r[1] = (short)__builtin_bit_cast(unsigned short, __float2bfloat16(b));
  r[2] = (short)__builtin_bit_cast(unsigned short, __float2bfloat16(c));
  r[3] = (short)__builtin_bit_cast(unsigned short, __float2bfloat16(d));
  return r;
}
static __device__ __forceinline__ short8 cvt8(f32x4 lo, f32x4 hi) {
  short8 r;
  r[0] = (short)f2bf(lo[0]); r[1] = (short)f2bf(lo[1]);
  r[2] = (short)f2bf(lo[2]); r[3] = (short)f2bf(lo[3]);
  r[4] = (short)f2bf(hi[0]); r[5] = (short)f2bf(hi[1]);
  r[6] = (short)f2bf(hi[2]); r[7] = (short)f2bf(hi[3]);
  return r;
}
static __device__ __forceinline__ short8 cvt8s(f32x4 lo, f32x4 hi, float s) {
  short8 r;
  r[0] = (short)f2bf(lo[0]*s); r[1] = (short)f2bf(lo[1]*s);
  r[2] = (short)f2bf(lo[2]*s); r[3] = (short)f2bf(lo[3]*s);
  r[4] = (short)f2bf(hi[0]*s); r[5] = (short)f2bf(hi[1]*s);
  r[6] = (short)f2bf(hi[2]*s); r[7] = (short)f2bf(hi[3]*s);
  return r;
}
// async global -> LDS, 16B/lane (used only in gemm, where it measured faster)
static __device__ __forceinline__ void gl_lds16(const void* g, void* l) {
  __builtin_amdgcn_global_load_lds(
      (const __attribute__((address_space(1))) unsigned int*)g,
      (__attribute__((address_space(3))) unsigned int*)l, 16, 0, 0);
}

// ---------------------------------------------------------------------------
// 1) Fused prep: [0,256) transpose W; [256,384) transpose conv kernels;
// [384,896) pack mask bits. One launch instead of three.
__global__ __launch_bounds__(256) void prep_kernel(
    const float* __restrict__ W, unsigned short* __restrict__ WT,
    const float* __restrict__ kck, unsigned short* __restrict__ kkT,
    const float* __restrict__ vck, unsigned short* __restrict__ vkT,
    const int* __restrict__ msk, unsigned int* __restrict__ mpk) {
  __shared__ unsigned short t[64][72];
  const int bid = blockIdx.x;
  const int tid = threadIdx.x;
  if (bid < 256) {                       // W (1024x1024 f32 [k][n]) -> WT bf16 [n][k]
    const int k0 = (bid & 15) * 64, n0 = (bid >> 4) * 64;
    const int cr = tid >> 4, cc = (tid & 15) * 4;
    #pragma unroll
    for (int it = 0; it < 4; ++it) {
      const int kk = it * 16 + cr;
      const f32x4 v = *(const f32x4*)(W + (size_t)(k0 + kk) * 1024 + n0 + cc);
      #pragma unroll
      for (int j = 0; j < 4; ++j) t[cc + j][kk] = f2bf(v[j]);
    }
    __syncthreads();
    const int rn = tid >> 2, seg = tid & 3;
    const short8 w0 = *(const short8*)(&t[rn][seg * 16]);
    const short8 w1 = *(const short8*)(&t[rn][seg * 16 + 8]);
    unsigned short* op = WT + (size_t)(n0 + rn) * 1024 + k0 + seg * 16;
    *(short8*)op = w0;
    *(short8*)(op + 8) = w1;
  } else if (bid < 384) {                // conv kernels (4,64,64) -> [o][w*64+i]
    const int tb = bid - 256;
    const float* K = (tb < 64) ? kck : vck;
    unsigned short* KT = (tb < 64) ? kkT : vkT;
    const int idx = (tb & 63) * 256 + tid;
    const int kk = idx >> 6, o = idx & 63;
    KT[o * 256 + kk] = f2bf(K[idx]);
  } else {                               // mask int32 -> bit-packed u32
    const int w = (bid - 384) * 256 + tid;
    const int* p = msk + (size_t)w * 32;
    unsigned int b = 0;
    #pragma unroll
    for (int i = 0; i < 8; ++i) {
      const int4e v = *(const int4e*)(p + i * 4);
      b |= (unsigned int)(v[0] & 1) << (i * 4);
      b |= (unsigned int)(v[1] & 1) << (i * 4 + 1);
      b |= (unsigned int)(v[2] & 1) << (i * 4 + 2);
      b |= (unsigned int)(v[3] & 1) << (i * 4 + 3);
    }
    mpk[w] = b;
  }
}

// ---------------------------------------------------------------------------
// 2) Strided conv1d compression as MFMA GEMM; K and V halves in ONE launch.
__global__ __launch_bounds__(256) void compress_kernel(
    const float* __restrict__ srcK, const unsigned short* __restrict__ kTK,
    const float* __restrict__ biasK, unsigned short* __restrict__ dstK,
    const float* __restrict__ srcV, const unsigned short* __restrict__ kTV,
    const float* __restrict__ biasV, unsigned short* __restrict__ dstV) {
  const int bid = blockIdx.x;
  const int tpose = bid >> 9;
  const float* src = tpose ? srcV : srcK;
  const unsigned short* kT = tpose ? kTV : kTK;
  const float* bias = tpose ? biasV : biasK;
  unsigned short* dst = tpose ? dstV : dstK;
  const int tid = threadIdx.x;
  const int wid = tid >> 6, lane = tid & 63;
  const int q = lane & 15, g = lane >> 4;
  const int R0 = ((bid & 511) * 4 + wid) * 16;
  const int row = R0 + q;
  const int bh = row >> 9, c = row & 511;
  const int b = bh >> 4, h = bh & 15;
  const float* sb = src + (((size_t)b * 2048 + (size_t)c * 4) * 16 + h) * 64;
  f32x4 acc[4];
  #pragma unroll
  for (int ct = 0; ct < 4; ++ct) acc[ct] = f32x4{0.f, 0.f, 0.f, 0.f};
  #pragma unroll
  for (int ch = 0; ch < 8; ++ch) {
    const int kk = ch * 32 + g * 8;
    const int w = kk >> 6, i = kk & 63;
    const float* s8 = sb + (size_t)w * 1024 + i;
    short8 a = cvt8(*(const f32x4*)s8, *(const f32x4*)(s8 + 4));
    #pragma unroll
    for (int ct = 0; ct < 4; ++ct) {
      short8 bf = *(const short8*)(kT + (ct * 16 + q) * 256 + ch * 32 + g * 8);
      acc[ct] = MFMA32(a, bf, acc[ct]);
    }
  }
  const int ro = R0 + 4 * g;
  #pragma unroll
  for (int ct = 0; ct < 4; ++ct) {
    const int col = ct * 16 + q;
    const float bv = bias[col];
    #pragma unroll
    for (int r = 0; r < 4; ++r) {
      const unsigned short val = f2bf(acc[ct][r] + bv);
      const int rr = ro + r;
      if (tpose) dst[(size_t)(rr >> 9) * 32768 + (size_t)col * 512 + (rr & 511)] = val;
      else       dst[(size_t)rr * 64 + col] = val;
    }
  }
}

// ---------------------------------------------------------------------------
// 3) Attention v11: 64-key superchunks (8 barriers, not 32). K staged to LDS
// [64][72] double-buffered via reg-staging (cache path). V read directly from
// global into regs (all 4 waves read identical bytes -> L1 serves 3/4; no V
// staging ops, no V LDS conflicts). P never leaves registers (K=16 PV).
// Epilogue LDS rows at stride 144B (bank varies with q -> no 16-way).
__global__ __launch_bounds__(256) void attn_kernel(
    const float* __restrict__ preq, const unsigned int* __restrict__ mpk,
    const unsigned short* __restrict__ kc, const unsigned short* __restrict__ vt,
    unsigned short* __restrict__ merged) {
  __shared__ unsigned short Kl[2][64 * 72];   // 18432 B; epilogue reuses
  const int tid = threadIdx.x;
  const int wid = tid >> 6, lane = tid & 63;
  const int q = lane & 15, g = lane >> 4;
  // XCD swizzle: bid&7 = XCD; per XCD one bp, 8 hp -> K/V/mask L2-resident.
  const int bid = blockIdx.x;
  const int x = bid & 7, ii = bid >> 3;              // ii in 0..127
  const int bp = x >> 1;
  const int hp = ((x & 1) << 3) | (ii & 7);
  const int tile = ii >> 3;                          // 16 tiles of 128 q-rows
  const int jj = hp * 4 + bp;
  const int bin = jj >> 4, hin = jj & 15;
  const int s0 = tile * 128 + wid * 32;

  const float QS = 0.18033688f;    // 0.125 * log2(e)
  const float* qpA = preq + (((size_t)bin * 2048 + s0 + q) * 16 + hin) * 64;
  const float* qpB = qpA + 16 * 1024;
  const short8 bqA0 = cvt8s(*(const f32x4*)(qpA + g * 8), *(const f32x4*)(qpA + g * 8 + 4), QS);
  const short8 bqA1 = cvt8s(*(const f32x4*)(qpA + 32 + g * 8), *(const f32x4*)(qpA + 32 + g * 8 + 4), QS);
  const short8 bqB0 = cvt8s(*(const f32x4*)(qpB + g * 8), *(const f32x4*)(qpB + g * 8 + 4), QS);
  const short8 bqB1 = cvt8s(*(const f32x4*)(qpB + 32 + g * 8), *(const f32x4*)(qpB + 32 + g * 8 + 4), QS);

  const unsigned short* kcb = kc + (size_t)jj * 512 * 64;
  const unsigned short* vtb = vt + (size_t)(bp * 16 + hp) * 64 * 512;
  const unsigned int* mrowA = mpk + ((size_t)bp * 2048 + s0 + q) * 16;
  const unsigned int* mrowB = mrowA + 256;

  // K staging: 64 rows x 128B per superchunk; thread handles rows r0 and r0+32.
  const int r0 = tid >> 3, seg = tid & 7;
  const unsigned short* gK0 = kcb + (size_t)r0 * 64 + seg * 8;
  const unsigned short* gK1 = gK0 + 32 * 64;
  unsigned short* lK0 = &Kl[0][0] + r0 * 72 + seg * 8;
  unsigned short* lK1 = lK0 + 32 * 72;

  // V frag base (global): dh row = o*16+q, key = sc*64 + sub*16 + g*4
  const unsigned short* vbase = vtb + (size_t)q * 512 + g * 4;

  const short4v one4 = {(short)0x3F80, (short)0x3F80, (short)0x3F80, (short)0x3F80};

  f32x4 oA[4], oB[4];
  #pragma unroll
  for (int o = 0; o < 4; ++o) { oA[o] = f32x4{0,0,0,0}; oB[o] = f32x4{0,0,0,0}; }
  f32x4 oSA = {0,0,0,0}, oSB = {0,0,0,0};     // row-sum accumulators

  // prologue: stage superchunk 0 into buf 0; load its mask words
  *(short8*)lK0 = *(const short8*)gK0;
  *(short8*)lK1 = *(const short8*)gK1;
  u32x2 mA2 = *(const u32x2*)(mrowA);
  u32x2 mB2 = *(const u32x2*)(mrowB);
  __syncthreads();

  #pragma unroll 2
  for (int sc = 0; sc < 8; ++sc) {
    // prefetch next superchunk's K + mask into rotation regs
    short8 nK0, nK1;
    u32x2 nmA2 = {0, 0}, nmB2 = {0, 0};
    if (sc < 7) {
      nK0 = *(const short8*)(gK0 + (size_t)(sc + 1) * 4096);
      nK1 = *(const short8*)(gK1 + (size_t)(sc + 1) * 4096);
      nmA2 = *(const u32x2*)(mrowA + 2 * (sc + 1));
      nmB2 = *(const u32x2*)(mrowB + 2 * (sc + 1));
    }
    // V frags for THIS superchunk (global; consumed after the QK section)
    short4v vf[4][4];
    #pragma unroll
    for (int o = 0; o < 4; ++o)
      #pragma unroll
      for (int sub = 0; sub < 4; ++sub)
        vf[o][sub] = *(const short4v*)(vbase + o * 16 * 512 + sc * 64 + sub * 16);

    const unsigned short* Kc_ = &Kl[sc & 1][0];
    short4v pA[4], pB[4];
    __builtin_amdgcn_s_setprio(1);
    #pragma unroll
    for (int sub = 0; sub < 4; ++sub) {
      const short8 k0 = *(const short8*)(Kc_ + (sub * 16 + q) * 72 + g * 8);
      const short8 k1 = *(const short8*)(Kc_ + (sub * 16 + q) * 72 + 32 + g * 8);
      f32x4 sA = {0,0,0,0}; sA = MFMA32(k0, bqA0, sA); sA = MFMA32(k1, bqA1, sA);
      f32x4 sB = {0,0,0,0}; sB = MFMA32(k0, bqB0, sB); sB = MFMA32(k1, bqB1, sB);
      const unsigned int wA = mA2[sub >> 1], wB = mB2[sub >> 1];
      const int bb = (sub & 1) * 16 + 4 * g;
      float eA[4], eB[4];
      #pragma unroll
      for (int r = 0; r < 4; ++r) {
        eA[r] = ((wA >> (bb + r)) & 1u) ? __builtin_amdgcn_exp2f(sA[r]) : 0.0f;
        eB[r] = ((wB >> (bb + r)) & 1u) ? __builtin_amdgcn_exp2f(sB[r]) : 0.0f;
      }
      pA[sub] = pk4(eA[0], eA[1], eA[2], eA[3]);
      pB[sub] = pk4(eB[0], eB[1], eB[2], eB[3]);
    }
    // PV: O^T[dh][q] += V^T . P^T (K=16, P direct from regs); ones row-sums
    #pragma unroll
    for (int o = 0; o < 4; ++o)
      #pragma unroll
      for (int sub = 0; sub < 4; ++sub) {
        oA[o] = MFMA16(vf[o][sub], pA[sub], oA[o]);
        oB[o] = MFMA16(vf[o][sub], pB[sub], oB[o]);
      }
    #pragma unroll
    for (int sub = 0; sub < 4; ++sub) {
      oSA = MFMA16(one4, pA[sub], oSA);
      oSB = MFMA16(one4, pB[sub], oSB);
    }
    __builtin_amdgcn_s_setprio(0);
    // stage next superchunk into the opposite buffer
    if (sc < 7) {
      *(short8*)(lK0 + ((sc + 1) & 1) * 4608) = nK0;
      *(short8*)(lK1 + ((sc + 1) & 1) * 4608) = nK1;
    }
    __syncthreads();                 // one barrier per 64 keys
    mA2 = nmA2; mB2 = nmB2;
  }

  const float rlA = 1.0f / oSA[0], rlB = 1.0f / oSB[0];

  // Epilogue: O^T regs -> LDS rows at stride 72h (bank varies with q),
  // then coalesced bf16 stores. Reuses Kl (post-loop barrier already done).
  unsigned short* eb = &Kl[0][0] + wid * 2304;     // 2 qsets x 16 x 72
  #pragma unroll
  for (int qs = 0; qs < 2; ++qs) {
    unsigned int* U = (unsigned int*)(eb + qs * 1152);
    const float rl = qs ? rlB : rlA;
    #pragma unroll
    for (int o = 0; o < 4; ++o) {
      const f32x4 ov = qs ? oB[o] : oA[o];
      U[q * 36 + o * 8 + 2 * g]     = pack2c(ov[0] * rl, ov[1] * rl);
      U[q * 36 + o * 8 + 2 * g + 1] = pack2c(ov[2] * rl, ov[3] * rl);
    }
  }
  const int ir = lane >> 2, sg2 = lane & 3;
  #pragma unroll
  for (int qs = 0; qs < 2; ++qs) {
    const unsigned short* ep = eb + qs * 1152;
    const short8 w0 = *(const short8*)(ep + ir * 72 + sg2 * 16);
    const short8 w1 = *(const short8*)(ep + ir * 72 + sg2 * 16 + 8);
    unsigned short* mp = merged + ((size_t)(bp * 2048 + s0 + qs * 16 + ir)) * 1024 + hp * 64 + sg2 * 16;
    *(short8*)mp = w0;
    *(short8*)(mp + 8) = w1;
  }
}

// ---------------------------------------------------------------------------
// 4) Output projection with cooperative B staging (v4, measured faster).
__global__ __launch_bounds__(256, 4) void gemm_kernel(
    const unsigned short* __restrict__ A, const unsigned short* __restrict__ BT,
    float* __restrict__ out) {
  __shared__ unsigned short Bb[2][4096];   // 128 n x 64B (32k), XOR-swizzled
  const int tid = threadIdx.x;
  const int wid = tid >> 6, lane = tid & 63;
  const int q = lane & 15, g = lane >> 4;
  const int bid = blockIdx.x;
  const int x = bid & 7, i = bid >> 3;
  const int N0 = (i & 7) * 128;
  const int M0 = (x * 8 + (i >> 3)) * 128 + wid * 32;

  const int r0 = wid * 32 + (lane >> 2);
  const int r1 = r0 + 16;
  const int sc = (lane & 3) * 16;
  const int b0 = sc ^ (((r0 >> 2) & 3) << 4);
  const int b1 = sc ^ (((r1 >> 2) & 3) << 4);
  const unsigned short* gs0 = BT + (size_t)(N0 + r0) * 1024 + (b0 >> 1);
  const unsigned short* gs1 = BT + (size_t)(N0 + r1) * 1024 + (b1 >> 1);
  const int bsz = ((q >> 2) & 3) << 4;

  f32x4 acc[2][8];
  #pragma unroll
  for (int rt = 0; rt < 2; ++rt)
    #pragma unroll
    for (int ct = 0; ct < 8; ++ct) acc[rt][ct] = f32x4{0.f, 0.f, 0.f, 0.f};
  const unsigned short* a0p = A + (size_t)(M0 + q) * 1024 + g * 8;
  const unsigned short* a1p = a0p + 16 * 1024;

  gl_lds16(gs0, &Bb[0][wid * 1024]);
  gl_lds16(gs1, &Bb[0][wid * 1024 + 512]);
  short8 a0 = *(const short8*)a0p;
  short8 a1 = *(const short8*)a1p;
  __syncthreads();

  for (int t = 0; t < 32; ++t) {
    if (t < 31) {
      gl_lds16(gs0 + (t + 1) * 32, &Bb[(t + 1) & 1][wid * 1024]);
      gl_lds16(gs1 + (t + 1) * 32, &Bb[(t + 1) & 1][wid * 1024 + 512]);
    }
    short8 a0n = a0, a1n = a1;
    if (t < 31) {
      a0n = *(const short8*)(a0p + (t + 1) * 32);
      a1n = *(const short8*)(a1p + (t + 1) * 32);
    }
    const unsigned short* Bc = &Bb[t & 1][0];
    #pragma unroll
    for (int ct = 0; ct < 8; ++ct) {
      const short8 b = *(const short8*)(Bc + (ct * 16 + q) * 32 + (((g * 16) ^ bsz) >> 1));
      acc[0][ct] = MFMA32(a0, b, acc[0][ct]);
      acc[1][ct] = MFMA32(a1, b, acc[1][ct]);
    }
    a0 = a0n; a1 = a1n;
    __syncthreads();
  }
  #pragma unroll
  for (int rt = 0; rt < 2; ++rt)
    #pragma unroll
    for (int ct = 0; ct < 8; ++ct)
      #pragma unroll
      for (int r = 0; r < 4; ++r)
        out[(size_t)(M0 + rt * 16 + 4 * g + r) * 1024 + N0 + ct * 16 + q] = acc[rt][ct][r];
}

// ---------------------------------------------------------------------------
extern "C" void kernel_launch(void* const* d_in, const int* in_sizes, int n_in,
                              void* d_out, int out_size, void* d_ws, size_t ws_size,
                              hipStream_t stream) {
  const float* preq = (const float*)d_in[0];
  const float* prev = (const float*)d_in[1];
  const float* prek = (const float*)d_in[2];
  const float* W    = (const float*)d_in[3];
  const float* kck  = (const float*)d_in[4];
  const float* kcb  = (const float*)d_in[5];
  const float* vck  = (const float*)d_in[6];
  const float* vcb  = (const float*)d_in[7];
  const int*   msk  = (const int*)d_in[8];
  float* out = (float*)d_out;

  char* ws = (char*)d_ws;
  unsigned short* WT  = (unsigned short*)(ws);                      // 2 MB
  unsigned short* kkT = (unsigned short*)(ws + 2097152);            // 64 KB
  unsigned short* vkT = (unsigned short*)(ws + 2129920);            // 64 KB
  unsigned short* kcB = (unsigned short*)(ws + 2162688);            // 4 MB  [bh][c][dh]
  unsigned short* vcT = (unsigned short*)(ws + 6356992);            // 4 MB  [bh][dh][c]
  unsigned short* mrg = (unsigned short*)(ws + 10551296);           // 16 MB [8192][1024]
  unsigned int*   mpk = (unsigned int*)(ws + 27328512);             // 512 KB packed mask

  hipLaunchKernelGGL(prep_kernel, dim3(896), dim3(256), 0, stream,
                     W, WT, kck, kkT, vck, vkT, msk, mpk);
  hipLaunchKernelGGL(compress_kernel, dim3(1024), dim3(256), 0, stream,
                     prek, kkT, kcb, kcB, prev, vkT, vcb, vcT);
  hipLaunchKernelGGL(attn_kernel, dim3(1024), dim3(256), 0, stream, preq, mpk, kcB, vcT, mrg);
  hipLaunchKernelGGL(gemm_kernel, dim3(512), dim3(256), 0, stream, mrg, WT, out);
}

// Round 12
// 107.981 us; speedup vs baseline: 1.3041x; 1.3041x over previous
//
#include <hip/hip_runtime.h>
#include <hip/hip_bf16.h>

// Problem constants (fixed by setup_inputs): B=4, S=2048, H=16, DH=64, W=4,
// Kc=512, D=1024. Output (4,2048,1024) f32.

typedef __attribute__((ext_vector_type(8))) short short8;   // 8 bf16 (4 VGPRs)
typedef __attribute__((ext_vector_type(4))) short short4v;  // 4 bf16 (2 VGPRs)
typedef __attribute__((ext_vector_type(4))) float f32x4;
typedef __attribute__((ext_vector_type(4))) int int4e;

#define MFMA32(A, Bf, C) __builtin_amdgcn_mfma_f32_16x16x32_bf16((A), (Bf), (C), 0, 0, 0)
#define MFMA16(A, Bf, C) __builtin_amdgcn_mfma_f32_16x16x16bf16_1k((A), (Bf), (C), 0, 0, 0)

static __device__ __forceinline__ unsigned short f2bf(float f) {
  unsigned int u = __builtin_bit_cast(unsigned int, f);
  u += 0x7fffu + ((u >> 16) & 1u);   // RNE (finite inputs only)
  return (unsigned short)(u >> 16);
}
static __device__ __forceinline__ unsigned int pack2c(float a, float b) {
  unsigned short lo = __builtin_bit_cast(unsigned short, __float2bfloat16(a));
  unsigned short hi = __builtin_bit_cast(unsigned short, __float2bfloat16(b));
  return (unsigned int)lo | ((unsigned int)hi << 16);
}
static __device__ __forceinline__ short4v pk4(float a, float b, float c, float d) {
  short4v r;
  r[0] = (short)__builtin_bit_cast(unsigned short, __float2bfloat16(a));
  r[1] = (short)__builtin_bit_cast(unsigned short, __float2bfloat16(b));
  r[2] = (short)__builtin_bit_cast(unsigned short, __float2bfloat16(c));
  r[3] = (short)__builtin_bit_cast(unsigned short, __float2bfloat16(d));
  return r;
}
static __device__ __forceinline__ short8 cvt8(f32x4 lo, f32x4 hi) {
  short8 r;
  r[0] = (short)f2bf(lo[0]); r[1] = (short)f2bf(lo[1]);
  r[2] = (short)f2bf(lo[2]); r[3] = (short)f2bf(lo[3]);
  r[4] = (short)f2bf(hi[0]); r[5] = (short)f2bf(hi[1]);
  r[6] = (short)f2bf(hi[2]); r[7] = (short)f2bf(hi[3]);
  return r;
}
static __device__ __forceinline__ short8 cvt8s(f32x4 lo, f32x4 hi, float s) {
  short8 r;
  r[0] = (short)f2bf(lo[0]*s); r[1] = (short)f2bf(lo[1]*s);
  r[2] = (short)f2bf(lo[2]*s); r[3] = (short)f2bf(lo[3]*s);
  r[4] = (short)f2bf(hi[0]*s); r[5] = (short)f2bf(hi[1]*s);
  r[6] = (short)f2bf(hi[2]*s); r[7] = (short)f2bf(hi[3]*s);
  return r;
}
// async global -> LDS, 16B/lane (used only in gemm, where it measured faster)
static __device__ __forceinline__ void gl_lds16(const void* g, void* l) {
  __builtin_amdgcn_global_load_lds(
      (const __attribute__((address_space(1))) unsigned int*)g,
      (__attribute__((address_space(3))) unsigned int*)l, 16, 0, 0);
}

// ---------------------------------------------------------------------------
// 1) Fused prep: [0,256) transpose W; [256,384) transpose conv kernels;
// [384,896) pack mask bits.
__global__ __launch_bounds__(256) void prep_kernel(
    const float* __restrict__ W, unsigned short* __restrict__ WT,
    const float* __restrict__ kck, unsigned short* __restrict__ kkT,
    const float* __restrict__ vck, unsigned short* __restrict__ vkT,
    const int* __restrict__ msk, unsigned int* __restrict__ mpk) {
  __shared__ unsigned short t[64][72];
  const int bid = blockIdx.x;
  const int tid = threadIdx.x;
  if (bid < 256) {                       // W (1024x1024 f32 [k][n]) -> WT bf16 [n][k]
    const int k0 = (bid & 15) * 64, n0 = (bid >> 4) * 64;
    const int cr = tid >> 4, cc = (tid & 15) * 4;
    #pragma unroll
    for (int it = 0; it < 4; ++it) {
      const int kk = it * 16 + cr;
      const f32x4 v = *(const f32x4*)(W + (size_t)(k0 + kk) * 1024 + n0 + cc);
      #pragma unroll
      for (int j = 0; j < 4; ++j) t[cc + j][kk] = f2bf(v[j]);
    }
    __syncthreads();
    const int rn = tid >> 2, seg = tid & 3;
    const short8 w0 = *(const short8*)(&t[rn][seg * 16]);
    const short8 w1 = *(const short8*)(&t[rn][seg * 16 + 8]);
    unsigned short* op = WT + (size_t)(n0 + rn) * 1024 + k0 + seg * 16;
    *(short8*)op = w0;
    *(short8*)(op + 8) = w1;
  } else if (bid < 384) {                // conv kernels (4,64,64) -> [o][w*64+i]
    const int tb = bid - 256;
    const float* K = (tb < 64) ? kck : vck;
    unsigned short* KT = (tb < 64) ? kkT : vkT;
    const int idx = (tb & 63) * 256 + tid;
    const int kk = idx >> 6, o = idx & 63;
    KT[o * 256 + kk] = f2bf(K[idx]);
  } else {                               // mask int32 -> bit-packed u32
    const int w = (bid - 384) * 256 + tid;
    const int* p = msk + (size_t)w * 32;
    unsigned int b = 0;
    #pragma unroll
    for (int i = 0; i < 8; ++i) {
      const int4e v = *(const int4e*)(p + i * 4);
      b |= (unsigned int)(v[0] & 1) << (i * 4);
      b |= (unsigned int)(v[1] & 1) << (i * 4 + 1);
      b |= (unsigned int)(v[2] & 1) << (i * 4 + 2);
      b |= (unsigned int)(v[3] & 1) << (i * 4 + 3);
    }
    mpk[w] = b;
  }
}

// ---------------------------------------------------------------------------
// 2) Strided conv1d compression as MFMA GEMM; K and V halves in ONE launch.
__global__ __launch_bounds__(256) void compress_kernel(
    const float* __restrict__ srcK, const unsigned short* __restrict__ kTK,
    const float* __restrict__ biasK, unsigned short* __restrict__ dstK,
    const float* __restrict__ srcV, const unsigned short* __restrict__ kTV,
    const float* __restrict__ biasV, unsigned short* __restrict__ dstV) {
  const int bid = blockIdx.x;
  const int tpose = bid >> 9;
  const float* src = tpose ? srcV : srcK;
  const unsigned short* kT = tpose ? kTV : kTK;
  const float* bias = tpose ? biasV : biasK;
  unsigned short* dst = tpose ? dstV : dstK;
  const int tid = threadIdx.x;
  const int wid = tid >> 6, lane = tid & 63;
  const int q = lane & 15, g = lane >> 4;
  const int R0 = ((bid & 511) * 4 + wid) * 16;
  const int row = R0 + q;
  const int bh = row >> 9, c = row & 511;
  const int b = bh >> 4, h = bh & 15;
  const float* sb = src + (((size_t)b * 2048 + (size_t)c * 4) * 16 + h) * 64;
  f32x4 acc[4];
  #pragma unroll
  for (int ct = 0; ct < 4; ++ct) acc[ct] = f32x4{0.f, 0.f, 0.f, 0.f};
  #pragma unroll
  for (int ch = 0; ch < 8; ++ch) {
    const int kk = ch * 32 + g * 8;
    const int w = kk >> 6, i = kk & 63;
    const float* s8 = sb + (size_t)w * 1024 + i;
    short8 a = cvt8(*(const f32x4*)s8, *(const f32x4*)(s8 + 4));
    #pragma unroll
    for (int ct = 0; ct < 4; ++ct) {
      short8 bf = *(const short8*)(kT + (ct * 16 + q) * 256 + ch * 32 + g * 8);
      acc[ct] = MFMA32(a, bf, acc[ct]);
    }
  }
  const int ro = R0 + 4 * g;
  #pragma unroll
  for (int ct = 0; ct < 4; ++ct) {
    const int col = ct * 16 + q;
    const float bv = bias[col];
    #pragma unroll
    for (int r = 0; r < 4; ++r) {
      const unsigned short val = f2bf(acc[ct][r] + bv);
      const int rr = ro + r;
      if (tpose) dst[(size_t)(rr >> 9) * 32768 + (size_t)col * 512 + (rr & 511)] = val;
      else       dst[(size_t)rr * 64 + col] = val;
    }
  }
}

// ---------------------------------------------------------------------------
// 3) Attention v12 = v10 (measured 54.2us: 32-key chunks, K+V reg-staged LDS
// double-buffered, one barrier/chunk, P-in-registers K=16 PV, ones-MFMA
// row-sums) + v11's epilogue stride-72 fix (the measured conflict killer;
// v11's V-from-global is REVERTED — it serialized on scattered 8B gathers).
__global__ __launch_bounds__(256) void attn_kernel(
    const float* __restrict__ preq, const unsigned int* __restrict__ mpk,
    const unsigned short* __restrict__ kc, const unsigned short* __restrict__ vt,
    unsigned short* __restrict__ merged) {
  __shared__ unsigned short shm[9728];   // Kl 2x(32*72)=4608 | Vl 2x(64*40)=5120
  unsigned short* Kl = shm;              // + buf*(32*72)
  unsigned short* Vl = shm + 4608;       // + buf*(64*40)
  const int tid = threadIdx.x;
  const int wid = tid >> 6, lane = tid & 63;
  const int q = lane & 15, g = lane >> 4;
  // XCD swizzle: bid&7 = XCD; per XCD one bp, 8 hp -> K/V/mask L2-resident.
  const int bid = blockIdx.x;
  const int x = bid & 7, ii = bid >> 3;              // ii in 0..127
  const int bp = x >> 1;
  const int hp = ((x & 1) << 3) | (ii & 7);
  const int tile = ii >> 3;                          // 16 tiles of 128 q-rows
  const int jj = hp * 4 + bp;
  const int bin = jj >> 4, hin = jj & 15;
  const int s0 = tile * 128 + wid * 32;

  const float QS = 0.18033688f;    // 0.125 * log2(e)
  const float* qpA = preq + (((size_t)bin * 2048 + s0 + q) * 16 + hin) * 64;
  const float* qpB = qpA + 16 * 1024;
  const short8 bqA0 = cvt8s(*(const f32x4*)(qpA + g * 8), *(const f32x4*)(qpA + g * 8 + 4), QS);
  const short8 bqA1 = cvt8s(*(const f32x4*)(qpA + 32 + g * 8), *(const f32x4*)(qpA + 32 + g * 8 + 4), QS);
  const short8 bqB0 = cvt8s(*(const f32x4*)(qpB + g * 8), *(const f32x4*)(qpB + g * 8 + 4), QS);
  const short8 bqB1 = cvt8s(*(const f32x4*)(qpB + 32 + g * 8), *(const f32x4*)(qpB + 32 + g * 8 + 4), QS);

  const unsigned short* kcb = kc + (size_t)jj * 512 * 64;
  const unsigned short* vtb = vt + (size_t)(bp * 16 + hp) * 64 * 512;
  const unsigned int* mrowA = mpk + ((size_t)bp * 2048 + s0 + q) * 16;
  const unsigned int* mrowB = mrowA + 256;

  // Staging roles: K chunk = 32 rows x 128B -> 8 threads/row x 16B;
  //                V chunk = 64 rows x 64B  -> 4 threads/row x 16B.
  const int krow = tid >> 3, kc8 = tid & 7;
  const unsigned short* gK = kcb + (size_t)krow * 64 + kc8 * 8;
  unsigned short* lK = Kl + krow * 72 + kc8 * 8;
  const int vrow = tid >> 2, vc4 = tid & 3;
  const unsigned short* gV = vtb + (size_t)vrow * 512 + vc4 * 8;
  unsigned short* lV = Vl + vrow * 40 + vc4 * 8;

  const short4v one4 = {(short)0x3F80, (short)0x3F80, (short)0x3F80, (short)0x3F80};

  f32x4 oA[4], oB[4];
  #pragma unroll
  for (int o = 0; o < 4; ++o) { oA[o] = f32x4{0,0,0,0}; oB[o] = f32x4{0,0,0,0}; }
  f32x4 oSA = {0,0,0,0}, oSB = {0,0,0,0};     // row-sum accumulators (ones-MFMA)

  // prologue: stage chunk 0 into buf 0; load chunk-0 mask words
  {
    const short8 sK = *(const short8*)gK;
    const short8 sV = *(const short8*)gV;
    *(short8*)lK = sK;
    *(short8*)lV = sV;
  }
  unsigned int mA = mrowA[0], mB = mrowB[0];
  __syncthreads();

  #pragma unroll 2
  for (int c = 0; c < 16; ++c) {
    // issue next chunk's staging loads + mask now (covered by this chunk)
    short8 nK, nV;
    unsigned int nmA = 0, nmB = 0;
    if (c < 15) {
      nK = *(const short8*)(gK + (size_t)(c + 1) * 2048);
      nV = *(const short8*)(gV + (c + 1) * 32);
      nmA = mrowA[c + 1];
      nmB = mrowB[c + 1];
    }
    const unsigned short* Kc_ = Kl + (c & 1) * (32 * 72);
    const unsigned short* Vc_ = Vl + (c & 1) * (64 * 40);
    // K frags (b128)
    const short8 ka0 = *(const short8*)(Kc_ + q * 72 + g * 8);
    const short8 ka1 = *(const short8*)(Kc_ + q * 72 + 32 + g * 8);
    const short8 kb0 = *(const short8*)(Kc_ + (16 + q) * 72 + g * 8);
    const short8 kb1 = *(const short8*)(Kc_ + (16 + q) * 72 + 32 + g * 8);
    // V frags for K=16 PV: keys sub*16 + 4g..+3 at dh row o*16+q
    short4v vf[4][2];
    #pragma unroll
    for (int o = 0; o < 4; ++o) {
      vf[o][0] = *(const short4v*)(Vc_ + (o * 16 + q) * 40 + g * 4);
      vf[o][1] = *(const short4v*)(Vc_ + (o * 16 + q) * 40 + 16 + g * 4);
    }
    __builtin_amdgcn_s_setprio(1);
    // QK^T (swapped): S^T[key][q]; acc reg r = key sub*16 + 4g + r, col q
    f32x4 s0A = {0,0,0,0}; s0A = MFMA32(ka0, bqA0, s0A); s0A = MFMA32(ka1, bqA1, s0A);
    f32x4 s1A = {0,0,0,0}; s1A = MFMA32(kb0, bqA0, s1A); s1A = MFMA32(kb1, bqA1, s1A);
    f32x4 s0B = {0,0,0,0}; s0B = MFMA32(ka0, bqB0, s0B); s0B = MFMA32(ka1, bqB1, s0B);
    f32x4 s1B = {0,0,0,0}; s1B = MFMA32(kb0, bqB0, s1B); s1B = MFMA32(kb1, bqB1, s1B);
    // P = mask ? exp2(S') : 0
    float pA[8], pB[8];
    #pragma unroll
    for (int r = 0; r < 4; ++r) {
      const int b0 = 4 * g + r, b1 = 16 + 4 * g + r;
      pA[r]     = ((mA >> b0) & 1u) ? __builtin_amdgcn_exp2f(s0A[r]) : 0.0f;
      pA[4 + r] = ((mA >> b1) & 1u) ? __builtin_amdgcn_exp2f(s1A[r]) : 0.0f;
      pB[r]     = ((mB >> b0) & 1u) ? __builtin_amdgcn_exp2f(s0B[r]) : 0.0f;
      pB[4 + r] = ((mB >> b1) & 1u) ? __builtin_amdgcn_exp2f(s1B[r]) : 0.0f;
    }
    // pack P to bf16 B-frags IN REGISTERS (C/D layout == K=16 B layout)
    const short4v pA0 = pk4(pA[0], pA[1], pA[2], pA[3]);
    const short4v pA1 = pk4(pA[4], pA[5], pA[6], pA[7]);
    const short4v pB0 = pk4(pB[0], pB[1], pB[2], pB[3]);
    const short4v pB1 = pk4(pB[4], pB[5], pB[6], pB[7]);
    // PV: O^T[dh][q] += V^T . P^T via K=16 MFMAs; row-sums via ones-MFMA
    #pragma unroll
    for (int o = 0; o < 4; ++o) {
      oA[o] = MFMA16(vf[o][0], pA0, oA[o]);
      oA[o] = MFMA16(vf[o][1], pA1, oA[o]);
      oB[o] = MFMA16(vf[o][0], pB0, oB[o]);
      oB[o] = MFMA16(vf[o][1], pB1, oB[o]);
    }
    oSA = MFMA16(one4, pA0, oSA); oSA = MFMA16(one4, pA1, oSA);
    oSB = MFMA16(one4, pB0, oSB); oSB = MFMA16(one4, pB1, oSB);
    __builtin_amdgcn_s_setprio(0);
    // stage chunk c+1 into the opposite buffer
    if (c < 15) {
      *(short8*)(lK + ((c + 1) & 1) * (32 * 72)) = nK;
      *(short8*)(lV + ((c + 1) & 1) * (64 * 40)) = nV;
    }
    __syncthreads();                 // one barrier/chunk
    mA = nmA; mB = nmB;
  }

  const float rlA = 1.0f / oSA[0], rlB = 1.0f / oSB[0];

  // Epilogue (stride-72 rows -> bank varies with q, no 16-way conflicts):
  // O^T regs -> LDS -> coalesced bf16 stores. Reuses shm after final barrier.
  unsigned short* eb = shm + wid * 2304;           // per-wave 2 qsets x 16 x 72
  #pragma unroll
  for (int qs = 0; qs < 2; ++qs) {
    unsigned int* U = (unsigned int*)(eb + qs * 1152);
    const float rl = qs ? rlB : rlA;
    #pragma unroll
    for (int o = 0; o < 4; ++o) {
      const f32x4 ov = qs ? oB[o] : oA[o];
      U[q * 36 + o * 8 + 2 * g]     = pack2c(ov[0] * rl, ov[1] * rl);
      U[q * 36 + o * 8 + 2 * g + 1] = pack2c(ov[2] * rl, ov[3] * rl);
    }
  }
  const int ir = lane >> 2, sg2 = lane & 3;
  #pragma unroll
  for (int qs = 0; qs < 2; ++qs) {
    const unsigned short* ep = eb + qs * 1152;
    const short8 w0 = *(const short8*)(ep + ir * 72 + sg2 * 16);
    const short8 w1 = *(const short8*)(ep + ir * 72 + sg2 * 16 + 8);
    unsigned short* mp = merged + ((size_t)(bp * 2048 + s0 + qs * 16 + ir)) * 1024 + hp * 64 + sg2 * 16;
    *(short8*)mp = w0;
    *(short8*)(mp + 8) = w1;
  }
}

// ---------------------------------------------------------------------------
// 4) Output projection with cooperative B staging (v4, measured faster).
__global__ __launch_bounds__(256, 4) void gemm_kernel(
    const unsigned short* __restrict__ A, const unsigned short* __restrict__ BT,
    float* __restrict__ out) {
  __shared__ unsigned short Bb[2][4096];   // 128 n x 64B (32k), XOR-swizzled
  const int tid = threadIdx.x;
  const int wid = tid >> 6, lane = tid & 63;
  const int q = lane & 15, g = lane >> 4;
  const int bid = blockIdx.x;
  const int x = bid & 7, i = bid >> 3;
  const int N0 = (i & 7) * 128;
  const int M0 = (x * 8 + (i >> 3)) * 128 + wid * 32;

  const int r0 = wid * 32 + (lane >> 2);
  const int r1 = r0 + 16;
  const int sc = (lane & 3) * 16;
  const int b0 = sc ^ (((r0 >> 2) & 3) << 4);
  const int b1 = sc ^ (((r1 >> 2) & 3) << 4);
  const unsigned short* gs0 = BT + (size_t)(N0 + r0) * 1024 + (b0 >> 1);
  const unsigned short* gs1 = BT + (size_t)(N0 + r1) * 1024 + (b1 >> 1);
  const int bsz = ((q >> 2) & 3) << 4;

  f32x4 acc[2][8];
  #pragma unroll
  for (int rt = 0; rt < 2; ++rt)
    #pragma unroll
    for (int ct = 0; ct < 8; ++ct) acc[rt][ct] = f32x4{0.f, 0.f, 0.f, 0.f};
  const unsigned short* a0p = A + (size_t)(M0 + q) * 1024 + g * 8;
  const unsigned short* a1p = a0p + 16 * 1024;

  gl_lds16(gs0, &Bb[0][wid * 1024]);
  gl_lds16(gs1, &Bb[0][wid * 1024 + 512]);
  short8 a0 = *(const short8*)a0p;
  short8 a1 = *(const short8*)a1p;
  __syncthreads();

  for (int t = 0; t < 32; ++t) {
    if (t < 31) {
      gl_lds16(gs0 + (t + 1) * 32, &Bb[(t + 1) & 1][wid * 1024]);
      gl_lds16(gs1 + (t + 1) * 32, &Bb[(t + 1) & 1][wid * 1024 + 512]);
    }
    short8 a0n = a0, a1n = a1;
    if (t < 31) {
      a0n = *(const short8*)(a0p + (t + 1) * 32);
      a1n = *(const short8*)(a1p + (t + 1) * 32);
    }
    const unsigned short* Bc = &Bb[t & 1][0];
    #pragma unroll
    for (int ct = 0; ct < 8; ++ct) {
      const short8 b = *(const short8*)(Bc + (ct * 16 + q) * 32 + (((g * 16) ^ bsz) >> 1));
      acc[0][ct] = MFMA32(a0, b, acc[0][ct]);
      acc[1][ct] = MFMA32(a1, b, acc[1][ct]);
    }
    a0 = a0n; a1 = a1n;
    __syncthreads();
  }
  #pragma unroll
  for (int rt = 0; rt < 2; ++rt)
    #pragma unroll
    for (int ct = 0; ct < 8; ++ct)
      #pragma unroll
      for (int r = 0; r < 4; ++r)
        out[(size_t)(M0 + rt * 16 + 4 * g + r) * 1024 + N0 + ct * 16 + q] = acc[rt][ct][r];
}

// ---------------------------------------------------------------------------
extern "C" void kernel_launch(void* const* d_in, const int* in_sizes, int n_in,
                              void* d_out, int out_size, void* d_ws, size_t ws_size,
                              hipStream_t stream) {
  const float* preq = (const float*)d_in[0];
  const float* prev = (const float*)d_in[1];
  const float* prek = (const float*)d_in[2];
  const float* W    = (const float*)d_in[3];
  const float* kck  = (const float*)d_in[4];
  const float* kcb  = (const float*)d_in[5];
  const float* vck  = (const float*)d_in[6];
  const float* vcb  = (const float*)d_in[7];
  const int*   msk  = (const int*)d_in[8];
  float* out = (float*)d_out;

  char* ws = (char*)d_ws;
  unsigned short* WT  = (unsigned short*)(ws);                      // 2 MB
  unsigned short* kkT = (unsigned short*)(ws + 2097152);            // 64 KB
  unsigned short* vkT = (unsigned short*)(ws + 2129920);            // 64 KB
  unsigned short* kcB = (unsigned short*)(ws + 2162688);            // 4 MB  [bh][c][dh]
  unsigned short* vcT = (unsigned short*)(ws + 6356992);            // 4 MB  [bh][dh][c]
  unsigned short* mrg = (unsigned short*)(ws + 10551296);           // 16 MB [8192][1024]
  unsigned int*   mpk = (unsigned int*)(ws + 27328512);             // 512 KB packed mask

  hipLaunchKernelGGL(prep_kernel, dim3(896), dim3(256), 0, stream,
                     W, WT, kck, kkT, vck, vkT, msk, mpk);
  hipLaunchKernelGGL(compress_kernel, dim3(1024), dim3(256), 0, stream,
                     prek, kkT, kcb, kcB, prev, vkT, vcb, vcT);
  hipLaunchKernelGGL(attn_kernel, dim3(1024), dim3(256), 0, stream, preq, mpk, kcB, vcT, mrg);
  hipLaunchKernelGGL(gemm_kernel, dim3(512), dim3(256), 0, stream, mrg, WT, out);
}

// Round 13
// 107.470 us; speedup vs baseline: 1.3103x; 1.0048x over previous
//
#include <hip/hip_runtime.h>
#include <hip/hip_bf16.h>

// Problem constants (fixed by setup_inputs): B=4, S=2048, H=16, DH=64, W=4,
// Kc=512, D=1024. Output (4,2048,1024) f32.

typedef __attribute__((ext_vector_type(8))) short short8;   // 8 bf16 (4 VGPRs)
typedef __attribute__((ext_vector_type(4))) short short4v;  // 4 bf16 (2 VGPRs)
typedef __attribute__((ext_vector_type(4))) float f32x4;
typedef __attribute__((ext_vector_type(4))) int int4e;
typedef __attribute__((ext_vector_type(2))) unsigned int u32x2;

#define MFMA32(A, Bf, C) __builtin_amdgcn_mfma_f32_16x16x32_bf16((A), (Bf), (C), 0, 0, 0)
#define MFMA16(A, Bf, C) __builtin_amdgcn_mfma_f32_16x16x16bf16_1k((A), (Bf), (C), 0, 0, 0)

static __device__ __forceinline__ unsigned short f2bf(float f) {
  unsigned int u = __builtin_bit_cast(unsigned int, f);
  u += 0x7fffu + ((u >> 16) & 1u);   // RNE (finite inputs only)
  return (unsigned short)(u >> 16);
}
static __device__ __forceinline__ unsigned int pack2c(float a, float b) {
  unsigned short lo = __builtin_bit_cast(unsigned short, __float2bfloat16(a));
  unsigned short hi = __builtin_bit_cast(unsigned short, __float2bfloat16(b));
  return (unsigned int)lo | ((unsigned int)hi << 16);
}
// 4x f32 -> 4x bf16 via packed-pair conversions (v_cvt_pk_bf16_f32)
static __device__ __forceinline__ short4v pk4(float a, float b, float c, float d) {
  u32x2 t;
  t[0] = pack2c(a, b);
  t[1] = pack2c(c, d);
  return __builtin_bit_cast(short4v, t);
}
static __device__ __forceinline__ short8 cvt8(f32x4 lo, f32x4 hi) {
  short8 r;
  r[0] = (short)f2bf(lo[0]); r[1] = (short)f2bf(lo[1]);
  r[2] = (short)f2bf(lo[2]); r[3] = (short)f2bf(lo[3]);
  r[4] = (short)f2bf(hi[0]); r[5] = (short)f2bf(hi[1]);
  r[6] = (short)f2bf(hi[2]); r[7] = (short)f2bf(hi[3]);
  return r;
}
static __device__ __forceinline__ short8 cvt8s(f32x4 lo, f32x4 hi, float s) {
  short8 r;
  r[0] = (short)f2bf(lo[0]*s); r[1] = (short)f2bf(lo[1]*s);
  r[2] = (short)f2bf(lo[2]*s); r[3] = (short)f2bf(lo[3]*s);
  r[4] = (short)f2bf(hi[0]*s); r[5] = (short)f2bf(hi[1]*s);
  r[6] = (short)f2bf(hi[2]*s); r[7] = (short)f2bf(hi[3]*s);
  return r;
}
// async global -> LDS, 16B/lane (used only in gemm, where it measured faster)
static __device__ __forceinline__ void gl_lds16(const void* g, void* l) {
  __builtin_amdgcn_global_load_lds(
      (const __attribute__((address_space(1))) unsigned int*)g,
      (__attribute__((address_space(3))) unsigned int*)l, 16, 0, 0);
}

// ---------------------------------------------------------------------------
// 1) Fused prep: [0,256) transpose W; [256,384) transpose conv kernels;
// [384,896) pack mask bits.
__global__ __launch_bounds__(256) void prep_kernel(
    const float* __restrict__ W, unsigned short* __restrict__ WT,
    const float* __restrict__ kck, unsigned short* __restrict__ kkT,
    const float* __restrict__ vck, unsigned short* __restrict__ vkT,
    const int* __restrict__ msk, unsigned int* __restrict__ mpk) {
  __shared__ unsigned short t[64][72];
  const int bid = blockIdx.x;
  const int tid = threadIdx.x;
  if (bid < 256) {                       // W (1024x1024 f32 [k][n]) -> WT bf16 [n][k]
    const int k0 = (bid & 15) * 64, n0 = (bid >> 4) * 64;
    const int cr = tid >> 4, cc = (tid & 15) * 4;
    #pragma unroll
    for (int it = 0; it < 4; ++it) {
      const int kk = it * 16 + cr;
      const f32x4 v = *(const f32x4*)(W + (size_t)(k0 + kk) * 1024 + n0 + cc);
      #pragma unroll
      for (int j = 0; j < 4; ++j) t[cc + j][kk] = f2bf(v[j]);
    }
    __syncthreads();
    const int rn = tid >> 2, seg = tid & 3;
    const short8 w0 = *(const short8*)(&t[rn][seg * 16]);
    const short8 w1 = *(const short8*)(&t[rn][seg * 16 + 8]);
    unsigned short* op = WT + (size_t)(n0 + rn) * 1024 + k0 + seg * 16;
    *(short8*)op = w0;
    *(short8*)(op + 8) = w1;
  } else if (bid < 384) {                // conv kernels (4,64,64) -> [o][w*64+i]
    const int tb = bid - 256;
    const float* K = (tb < 64) ? kck : vck;
    unsigned short* KT = (tb < 64) ? kkT : vkT;
    const int idx = (tb & 63) * 256 + tid;
    const int kk = idx >> 6, o = idx & 63;
    KT[o * 256 + kk] = f2bf(K[idx]);
  } else {                               // mask int32 -> bit-packed u32
    const int w = (bid - 384) * 256 + tid;
    const int* p = msk + (size_t)w * 32;
    unsigned int b = 0;
    #pragma unroll
    for (int i = 0; i < 8; ++i) {
      const int4e v = *(const int4e*)(p + i * 4);
      b |= (unsigned int)(v[0] & 1) << (i * 4);
      b |= (unsigned int)(v[1] & 1) << (i * 4 + 1);
      b |= (unsigned int)(v[2] & 1) << (i * 4 + 2);
      b |= (unsigned int)(v[3] & 1) << (i * 4 + 3);
    }
    mpk[w] = b;
  }
}

// ---------------------------------------------------------------------------
// 2) Strided conv1d compression as MFMA GEMM; K and V halves in ONE launch.
// NEW: LDS-transpose epilogue -> fully coalesced 32B stores on BOTH paths
// (old V path scattered 2B stores at 1KB stride = ~8x write amplification).
__global__ __launch_bounds__(256) void compress_kernel(
    const float* __restrict__ srcK, const unsigned short* __restrict__ kTK,
    const float* __restrict__ biasK, unsigned short* __restrict__ dstK,
    const float* __restrict__ srcV, const unsigned short* __restrict__ kTV,
    const float* __restrict__ biasV, unsigned short* __restrict__ dstV) {
  __shared__ unsigned short t[64 * 72];
  const int bid = blockIdx.x;
  const int tpose = bid >> 9;
  const float* src = tpose ? srcV : srcK;
  const unsigned short* kT = tpose ? kTV : kTK;
  const float* bias = tpose ? biasV : biasK;
  unsigned short* dst = tpose ? dstV : dstK;
  const int tid = threadIdx.x;
  const int wid = tid >> 6, lane = tid & 63;
  const int q = lane & 15, g = lane >> 4;
  const int blockR0 = (bid & 511) * 64;        // 64 output rows per block
  const int R0 = blockR0 + wid * 16;
  const int row = R0 + q;
  const int bh = row >> 9, c = row & 511;
  const int b = bh >> 4, h = bh & 15;
  const float* sb = src + (((size_t)b * 2048 + (size_t)c * 4) * 16 + h) * 64;
  f32x4 acc[4];
  #pragma unroll
  for (int ct = 0; ct < 4; ++ct) acc[ct] = f32x4{0.f, 0.f, 0.f, 0.f};
  #pragma unroll
  for (int ch = 0; ch < 8; ++ch) {
    const int kk = ch * 32 + g * 8;
    const int w = kk >> 6, i = kk & 63;
    const float* s8 = sb + (size_t)w * 1024 + i;
    short8 a = cvt8(*(const f32x4*)s8, *(const f32x4*)(s8 + 4));
    #pragma unroll
    for (int ct = 0; ct < 4; ++ct) {
      short8 bf = *(const short8*)(kT + (ct * 16 + q) * 256 + ch * 32 + g * 8);
      acc[ct] = MFMA32(a, bf, acc[ct]);
    }
  }
  // epilogue: acc -> LDS (K: [c][dh], V: [dh][c]), barrier, coalesced stores
  #pragma unroll
  for (int ct = 0; ct < 4; ++ct) {
    const int col = ct * 16 + q;
    const float bv = bias[col];
    #pragma unroll
    for (int r = 0; r < 4; ++r) {
      const int lr = wid * 16 + 4 * g + r;     // local output row (c index)
      const unsigned short val = f2bf(acc[ct][r] + bv);
      t[tpose ? (col * 72 + lr) : (lr * 72 + col)] = val;
    }
  }
  __syncthreads();
  const int d = tid >> 2, sq = tid & 3;
  const short8 w0 = *(const short8*)(&t[d * 72 + sq * 16]);
  const short8 w1 = *(const short8*)(&t[d * 72 + sq * 16 + 8]);
  unsigned short* op;
  if (tpose) {
    const int bhb = blockR0 >> 9, cb = blockR0 & 511;
    op = dst + (size_t)bhb * 32768 + (size_t)d * 512 + cb + sq * 16;
  } else {
    op = dst + (size_t)(blockR0 + d) * 64 + sq * 16;
  }
  *(short8*)op = w0;
  *(short8*)(op + 8) = w1;
}

// ---------------------------------------------------------------------------
// 3) Attention v12 (measured 51.4us) unchanged except pk4 now uses packed-pair
// bf16 conversion.
__global__ __launch_bounds__(256) void attn_kernel(
    const float* __restrict__ preq, const unsigned int* __restrict__ mpk,
    const unsigned short* __restrict__ kc, const unsigned short* __restrict__ vt,
    unsigned short* __restrict__ merged) {
  __shared__ unsigned short shm[9728];   // Kl 2x(32*72)=4608 | Vl 2x(64*40)=5120
  unsigned short* Kl = shm;              // + buf*(32*72)
  unsigned short* Vl = shm + 4608;       // + buf*(64*40)
  const int tid = threadIdx.x;
  const int wid = tid >> 6, lane = tid & 63;
  const int q = lane & 15, g = lane >> 4;
  // XCD swizzle: bid&7 = XCD; per XCD one bp, 8 hp -> K/V/mask L2-resident.
  const int bid = blockIdx.x;
  const int x = bid & 7, ii = bid >> 3;              // ii in 0..127
  const int bp = x >> 1;
  const int hp = ((x & 1) << 3) | (ii & 7);
  const int tile = ii >> 3;                          // 16 tiles of 128 q-rows
  const int jj = hp * 4 + bp;
  const int bin = jj >> 4, hin = jj & 15;
  const int s0 = tile * 128 + wid * 32;

  const float QS = 0.18033688f;    // 0.125 * log2(e)
  const float* qpA = preq + (((size_t)bin * 2048 + s0 + q) * 16 + hin) * 64;
  const float* qpB = qpA + 16 * 1024;
  const short8 bqA0 = cvt8s(*(const f32x4*)(qpA + g * 8), *(const f32x4*)(qpA + g * 8 + 4), QS);
  const short8 bqA1 = cvt8s(*(const f32x4*)(qpA + 32 + g * 8), *(const f32x4*)(qpA + 32 + g * 8 + 4), QS);
  const short8 bqB0 = cvt8s(*(const f32x4*)(qpB + g * 8), *(const f32x4*)(qpB + g * 8 + 4), QS);
  const short8 bqB1 = cvt8s(*(const f32x4*)(qpB + 32 + g * 8), *(const f32x4*)(qpB + 32 + g * 8 + 4), QS);

  const unsigned short* kcb = kc + (size_t)jj * 512 * 64;
  const unsigned short* vtb = vt + (size_t)(bp * 16 + hp) * 64 * 512;
  const unsigned int* mrowA = mpk + ((size_t)bp * 2048 + s0 + q) * 16;
  const unsigned int* mrowB = mrowA + 256;

  // Staging roles: K chunk = 32 rows x 128B -> 8 threads/row x 16B;
  //                V chunk = 64 rows x 64B  -> 4 threads/row x 16B.
  const int krow = tid >> 3, kc8 = tid & 7;
  const unsigned short* gK = kcb + (size_t)krow * 64 + kc8 * 8;
  unsigned short* lK = Kl + krow * 72 + kc8 * 8;
  const int vrow = tid >> 2, vc4 = tid & 3;
  const unsigned short* gV = vtb + (size_t)vrow * 512 + vc4 * 8;
  unsigned short* lV = Vl + vrow * 40 + vc4 * 8;

  const short4v one4 = {(short)0x3F80, (short)0x3F80, (short)0x3F80, (short)0x3F80};

  f32x4 oA[4], oB[4];
  #pragma unroll
  for (int o = 0; o < 4; ++o) { oA[o] = f32x4{0,0,0,0}; oB[o] = f32x4{0,0,0,0}; }
  f32x4 oSA = {0,0,0,0}, oSB = {0,0,0,0};     // row-sum accumulators (ones-MFMA)

  // prologue: stage chunk 0 into buf 0; load chunk-0 mask words
  {
    const short8 sK = *(const short8*)gK;
    const short8 sV = *(const short8*)gV;
    *(short8*)lK = sK;
    *(short8*)lV = sV;
  }
  unsigned int mA = mrowA[0], mB = mrowB[0];
  __syncthreads();

  #pragma unroll 2
  for (int c = 0; c < 16; ++c) {
    // issue next chunk's staging loads + mask now (covered by this chunk)
    short8 nK, nV;
    unsigned int nmA = 0, nmB = 0;
    if (c < 15) {
      nK = *(const short8*)(gK + (size_t)(c + 1) * 2048);
      nV = *(const short8*)(gV + (c + 1) * 32);
      nmA = mrowA[c + 1];
      nmB = mrowB[c + 1];
    }
    const unsigned short* Kc_ = Kl + (c & 1) * (32 * 72);
    const unsigned short* Vc_ = Vl + (c & 1) * (64 * 40);
    // K frags (b128)
    const short8 ka0 = *(const short8*)(Kc_ + q * 72 + g * 8);
    const short8 ka1 = *(const short8*)(Kc_ + q * 72 + 32 + g * 8);
    const short8 kb0 = *(const short8*)(Kc_ + (16 + q) * 72 + g * 8);
    const short8 kb1 = *(const short8*)(Kc_ + (16 + q) * 72 + 32 + g * 8);
    // V frags for K=16 PV: keys sub*16 + 4g..+3 at dh row o*16+q
    short4v vf[4][2];
    #pragma unroll
    for (int o = 0; o < 4; ++o) {
      vf[o][0] = *(const short4v*)(Vc_ + (o * 16 + q) * 40 + g * 4);
      vf[o][1] = *(const short4v*)(Vc_ + (o * 16 + q) * 40 + 16 + g * 4);
    }
    __builtin_amdgcn_s_setprio(1);
    // QK^T (swapped): S^T[key][q]; acc reg r = key sub*16 + 4g + r, col q
    f32x4 s0A = {0,0,0,0}; s0A = MFMA32(ka0, bqA0, s0A); s0A = MFMA32(ka1, bqA1, s0A);
    f32x4 s1A = {0,0,0,0}; s1A = MFMA32(kb0, bqA0, s1A); s1A = MFMA32(kb1, bqA1, s1A);
    f32x4 s0B = {0,0,0,0}; s0B = MFMA32(ka0, bqB0, s0B); s0B = MFMA32(ka1, bqB1, s0B);
    f32x4 s1B = {0,0,0,0}; s1B = MFMA32(kb0, bqB0, s1B); s1B = MFMA32(kb1, bqB1, s1B);
    // P = mask ? exp2(S') : 0
    float pA[8], pB[8];
    #pragma unroll
    for (int r = 0; r < 4; ++r) {
      const int b0 = 4 * g + r, b1 = 16 + 4 * g + r;
      pA[r]     = ((mA >> b0) & 1u) ? __builtin_amdgcn_exp2f(s0A[r]) : 0.0f;
      pA[4 + r] = ((mA >> b1) & 1u) ? __builtin_amdgcn_exp2f(s1A[r]) : 0.0f;
      pB[r]     = ((mB >> b0) & 1u) ? __builtin_amdgcn_exp2f(s0B[r]) : 0.0f;
      pB[4 + r] = ((mB >> b1) & 1u) ? __builtin_amdgcn_exp2f(s1B[r]) : 0.0f;
    }
    // pack P to bf16 B-frags IN REGISTERS (C/D layout == K=16 B layout)
    const short4v pA0 = pk4(pA[0], pA[1], pA[2], pA[3]);
    const short4v pA1 = pk4(pA[4], pA[5], pA[6], pA[7]);
    const short4v pB0 = pk4(pB[0], pB[1], pB[2], pB[3]);
    const short4v pB1 = pk4(pB[4], pB[5], pB[6], pB[7]);
    // PV: O^T[dh][q] += V^T . P^T via K=16 MFMAs; row-sums via ones-MFMA
    #pragma unroll
    for (int o = 0; o < 4; ++o) {
      oA[o] = MFMA16(vf[o][0], pA0, oA[o]);
      oA[o] = MFMA16(vf[o][1], pA1, oA[o]);
      oB[o] = MFMA16(vf[o][0], pB0, oB[o]);
      oB[o] = MFMA16(vf[o][1], pB1, oB[o]);
    }
    oSA = MFMA16(one4, pA0, oSA); oSA = MFMA16(one4, pA1, oSA);
    oSB = MFMA16(one4, pB0, oSB); oSB = MFMA16(one4, pB1, oSB);
    __builtin_amdgcn_s_setprio(0);
    // stage chunk c+1 into the opposite buffer
    if (c < 15) {
      *(short8*)(lK + ((c + 1) & 1) * (32 * 72)) = nK;
      *(short8*)(lV + ((c + 1) & 1) * (64 * 40)) = nV;
    }
    __syncthreads();                 // one barrier/chunk
    mA = nmA; mB = nmB;
  }

  const float rlA = 1.0f / oSA[0], rlB = 1.0f / oSB[0];

  // Epilogue (stride-72 rows -> bank varies with q, no 16-way conflicts):
  // O^T regs -> LDS -> coalesced bf16 stores. Reuses shm after final barrier.
  unsigned short* eb = shm + wid * 2304;           // per-wave 2 qsets x 16 x 72
  #pragma unroll
  for (int qs = 0; qs < 2; ++qs) {
    unsigned int* U = (unsigned int*)(eb + qs * 1152);
    const float rl = qs ? rlB : rlA;
    #pragma unroll
    for (int o = 0; o < 4; ++o) {
      const f32x4 ov = qs ? oB[o] : oA[o];
      U[q * 36 + o * 8 + 2 * g]     = pack2c(ov[0] * rl, ov[1] * rl);
      U[q * 36 + o * 8 + 2 * g + 1] = pack2c(ov[2] * rl, ov[3] * rl);
    }
  }
  const int ir = lane >> 2, sg2 = lane & 3;
  #pragma unroll
  for (int qs = 0; qs < 2; ++qs) {
    const unsigned short* ep = eb + qs * 1152;
    const short8 w0 = *(const short8*)(ep + ir * 72 + sg2 * 16);
    const short8 w1 = *(const short8*)(ep + ir * 72 + sg2 * 16 + 8);
    unsigned short* mp = merged + ((size_t)(bp * 2048 + s0 + qs * 16 + ir)) * 1024 + hp * 64 + sg2 * 16;
    *(short8*)mp = w0;
    *(short8*)(mp + 8) = w1;
  }
}

// ---------------------------------------------------------------------------
// 4) Output projection with cooperative B staging (v4, measured faster).
__global__ __launch_bounds__(256, 4) void gemm_kernel(
    const unsigned short* __restrict__ A, const unsigned short* __restrict__ BT,
    float* __restrict__ out) {
  __shared__ unsigned short Bb[2][4096];   // 128 n x 64B (32k), XOR-swizzled
  const int tid = threadIdx.x;
  const int wid = tid >> 6, lane = tid & 63;
  const int q = lane & 15, g = lane >> 4;
  const int bid = blockIdx.x;
  const int x = bid & 7, i = bid >> 3;
  const int N0 = (i & 7) * 128;
  const int M0 = (x * 8 + (i >> 3)) * 128 + wid * 32;

  const int r0 = wid * 32 + (lane >> 2);
  const int r1 = r0 + 16;
  const int sc = (lane & 3) * 16;
  const int b0 = sc ^ (((r0 >> 2) & 3) << 4);
  const int b1 = sc ^ (((r1 >> 2) & 3) << 4);
  const unsigned short* gs0 = BT + (size_t)(N0 + r0) * 1024 + (b0 >> 1);
  const unsigned short* gs1 = BT + (size_t)(N0 + r1) * 1024 + (b1 >> 1);
  const int bsz = ((q >> 2) & 3) << 4;

  f32x4 acc[2][8];
  #pragma unroll
  for (int rt = 0; rt < 2; ++rt)
    #pragma unroll
    for (int ct = 0; ct < 8; ++ct) acc[rt][ct] = f32x4{0.f, 0.f, 0.f, 0.f};
  const unsigned short* a0p = A + (size_t)(M0 + q) * 1024 + g * 8;
  const unsigned short* a1p = a0p + 16 * 1024;

  gl_lds16(gs0, &Bb[0][wid * 1024]);
  gl_lds16(gs1, &Bb[0][wid * 1024 + 512]);
  short8 a0 = *(const short8*)a0p;
  short8 a1 = *(const short8*)a1p;
  __syncthreads();

  for (int t = 0; t < 32; ++t) {
    if (t < 31) {
      gl_lds16(gs0 + (t + 1) * 32, &Bb[(t + 1) & 1][wid * 1024]);
      gl_lds16(gs1 + (t + 1) * 32, &Bb[(t + 1) & 1][wid * 1024 + 512]);
    }
    short8 a0n = a0, a1n = a1;
    if (t < 31) {
      a0n = *(const short8*)(a0p + (t + 1) * 32);
      a1n = *(const short8*)(a1p + (t + 1) * 32);
    }
    const unsigned short* Bc = &Bb[t & 1][0];
    #pragma unroll
    for (int ct = 0; ct < 8; ++ct) {
      const short8 b = *(const short8*)(Bc + (ct * 16 + q) * 32 + (((g * 16) ^ bsz) >> 1));
      acc[0][ct] = MFMA32(a0, b, acc[0][ct]);
      acc[1][ct] = MFMA32(a1, b, acc[1][ct]);
    }
    a0 = a0n; a1 = a1n;
    __syncthreads();
  }
  #pragma unroll
  for (int rt = 0; rt < 2; ++rt)
    #pragma unroll
    for (int ct = 0; ct < 8; ++ct)
      #pragma unroll
      for (int r = 0; r < 4; ++r)
        out[(size_t)(M0 + rt * 16 + 4 * g + r) * 1024 + N0 + ct * 16 + q] = acc[rt][ct][r];
}

// ---------------------------------------------------------------------------
extern "C" void kernel_launch(void* const* d_in, const int* in_sizes, int n_in,
                              void* d_out, int out_size, void* d_ws, size_t ws_size,
                              hipStream_t stream) {
  const float* preq = (const float*)d_in[0];
  const float* prev = (const float*)d_in[1];
  const float* prek = (const float*)d_in[2];
  const float* W    = (const float*)d_in[3];
  const float* kck  = (const float*)d_in[4];
  const float* kcb  = (const float*)d_in[5];
  const float* vck  = (const float*)d_in[6];
  const float* vcb  = (const float*)d_in[7];
  const int*   msk  = (const int*)d_in[8];
  float* out = (float*)d_out;

  char* ws = (char*)d_ws;
  unsigned short* WT  = (unsigned short*)(ws);                      // 2 MB
  unsigned short* kkT = (unsigned short*)(ws + 2097152);            // 64 KB
  unsigned short* vkT = (unsigned short*)(ws + 2129920);            // 64 KB
  unsigned short* kcB = (unsigned short*)(ws + 2162688);            // 4 MB  [bh][c][dh]
  unsigned short* vcT = (unsigned short*)(ws + 6356992);            // 4 MB  [bh][dh][c]
  unsigned short* mrg = (unsigned short*)(ws + 10551296);           // 16 MB [8192][1024]
  unsigned int*   mpk = (unsigned int*)(ws + 27328512);             // 512 KB packed mask

  hipLaunchKernelGGL(prep_kernel, dim3(896), dim3(256), 0, stream,
                     W, WT, kck, kkT, vck, vkT, msk, mpk);
  hipLaunchKernelGGL(compress_kernel, dim3(1024), dim3(256), 0, stream,
                     prek, kkT, kcb, kcB, prev, vkT, vcb, vcT);
  hipLaunchKernelGGL(attn_kernel, dim3(1024), dim3(256), 0, stream, preq, mpk, kcB, vcT, mrg);
  hipLaunchKernelGGL(gemm_kernel, dim3(512), dim3(256), 0, stream, mrg, WT, out);
}

// Round 14
// 106.047 us; speedup vs baseline: 1.3279x; 1.0134x over previous
//
#include <hip/hip_runtime.h>
#include <hip/hip_bf16.h>

// Problem constants (fixed by setup_inputs): B=4, S=2048, H=16, DH=64, W=4,
// Kc=512, D=1024. Output (4,2048,1024) f32.

typedef __attribute__((ext_vector_type(8))) short short8;   // 8 bf16 (4 VGPRs)
typedef __attribute__((ext_vector_type(4))) short short4v;  // 4 bf16 (2 VGPRs)
typedef __attribute__((ext_vector_type(4))) float f32x4;
typedef __attribute__((ext_vector_type(4))) int int4e;
typedef __attribute__((ext_vector_type(2))) unsigned int u32x2;

#define MFMA32(A, Bf, C) __builtin_amdgcn_mfma_f32_16x16x32_bf16((A), (Bf), (C), 0, 0, 0)
#define MFMA16(A, Bf, C) __builtin_amdgcn_mfma_f32_16x16x16bf16_1k((A), (Bf), (C), 0, 0, 0)

static __device__ __forceinline__ unsigned short f2bf(float f) {
  unsigned int u = __builtin_bit_cast(unsigned int, f);
  u += 0x7fffu + ((u >> 16) & 1u);   // RNE (finite inputs only)
  return (unsigned short)(u >> 16);
}
static __device__ __forceinline__ unsigned int pack2c(float a, float b) {
  unsigned short lo = __builtin_bit_cast(unsigned short, __float2bfloat16(a));
  unsigned short hi = __builtin_bit_cast(unsigned short, __float2bfloat16(b));
  return (unsigned int)lo | ((unsigned int)hi << 16);
}
// 4x f32 -> 4x bf16 via packed-pair conversions (v_cvt_pk_bf16_f32)
static __device__ __forceinline__ short4v pk4(float a, float b, float c, float d) {
  u32x2 t;
  t[0] = pack2c(a, b);
  t[1] = pack2c(c, d);
  return __builtin_bit_cast(short4v, t);
}
static __device__ __forceinline__ short8 cvt8(f32x4 lo, f32x4 hi) {
  short8 r;
  r[0] = (short)f2bf(lo[0]); r[1] = (short)f2bf(lo[1]);
  r[2] = (short)f2bf(lo[2]); r[3] = (short)f2bf(lo[3]);
  r[4] = (short)f2bf(hi[0]); r[5] = (short)f2bf(hi[1]);
  r[6] = (short)f2bf(hi[2]); r[7] = (short)f2bf(hi[3]);
  return r;
}
static __device__ __forceinline__ short8 cvt8s(f32x4 lo, f32x4 hi, float s) {
  short8 r;
  r[0] = (short)f2bf(lo[0]*s); r[1] = (short)f2bf(lo[1]*s);
  r[2] = (short)f2bf(lo[2]*s); r[3] = (short)f2bf(lo[3]*s);
  r[4] = (short)f2bf(hi[0]*s); r[5] = (short)f2bf(hi[1]*s);
  r[6] = (short)f2bf(hi[2]*s); r[7] = (short)f2bf(hi[3]*s);
  return r;
}
// async global -> LDS, 16B/lane (used only in gemm, where it measured faster)
static __device__ __forceinline__ void gl_lds16(const void* g, void* l) {
  __builtin_amdgcn_global_load_lds(
      (const __attribute__((address_space(1))) unsigned int*)g,
      (__attribute__((address_space(3))) unsigned int*)l, 16, 0, 0);
}

// ---------------------------------------------------------------------------
// 1) Fused prep: [0,256) transpose W; [256,384) transpose conv kernels;
// [384,896) pack mask bits.
__global__ __launch_bounds__(256) void prep_kernel(
    const float* __restrict__ W, unsigned short* __restrict__ WT,
    const float* __restrict__ kck, unsigned short* __restrict__ kkT,
    const float* __restrict__ vck, unsigned short* __restrict__ vkT,
    const int* __restrict__ msk, unsigned int* __restrict__ mpk) {
  __shared__ unsigned short t[64][72];
  const int bid = blockIdx.x;
  const int tid = threadIdx.x;
  if (bid < 256) {                       // W (1024x1024 f32 [k][n]) -> WT bf16 [n][k]
    const int k0 = (bid & 15) * 64, n0 = (bid >> 4) * 64;
    const int cr = tid >> 4, cc = (tid & 15) * 4;
    #pragma unroll
    for (int it = 0; it < 4; ++it) {
      const int kk = it * 16 + cr;
      const f32x4 v = *(const f32x4*)(W + (size_t)(k0 + kk) * 1024 + n0 + cc);
      #pragma unroll
      for (int j = 0; j < 4; ++j) t[cc + j][kk] = f2bf(v[j]);
    }
    __syncthreads();
    const int rn = tid >> 2, seg = tid & 3;
    const short8 w0 = *(const short8*)(&t[rn][seg * 16]);
    const short8 w1 = *(const short8*)(&t[rn][seg * 16 + 8]);
    unsigned short* op = WT + (size_t)(n0 + rn) * 1024 + k0 + seg * 16;
    *(short8*)op = w0;
    *(short8*)(op + 8) = w1;
  } else if (bid < 384) {                // conv kernels (4,64,64) -> [o][w*64+i]
    const int tb = bid - 256;
    const float* K = (tb < 64) ? kck : vck;
    unsigned short* KT = (tb < 64) ? kkT : vkT;
    const int idx = (tb & 63) * 256 + tid;
    const int kk = idx >> 6, o = idx & 63;
    KT[o * 256 + kk] = f2bf(K[idx]);
  } else {                               // mask int32 -> bit-packed u32
    const int w = (bid - 384) * 256 + tid;
    const int* p = msk + (size_t)w * 32;
    unsigned int b = 0;
    #pragma unroll
    for (int i = 0; i < 8; ++i) {
      const int4e v = *(const int4e*)(p + i * 4);
      b |= (unsigned int)(v[0] & 1) << (i * 4);
      b |= (unsigned int)(v[1] & 1) << (i * 4 + 1);
      b |= (unsigned int)(v[2] & 1) << (i * 4 + 2);
      b |= (unsigned int)(v[3] & 1) << (i * 4 + 3);
    }
    mpk[w] = b;
  }
}

// ---------------------------------------------------------------------------
// 2) Strided conv1d compression as MFMA GEMM; K and V halves in ONE launch.
// LDS-transpose epilogue -> fully coalesced 32B stores on BOTH paths.
__global__ __launch_bounds__(256) void compress_kernel(
    const float* __restrict__ srcK, const unsigned short* __restrict__ kTK,
    const float* __restrict__ biasK, unsigned short* __restrict__ dstK,
    const float* __restrict__ srcV, const unsigned short* __restrict__ kTV,
    const float* __restrict__ biasV, unsigned short* __restrict__ dstV) {
  __shared__ unsigned short t[64 * 72];
  const int bid = blockIdx.x;
  const int tpose = bid >> 9;
  const float* src = tpose ? srcV : srcK;
  const unsigned short* kT = tpose ? kTV : kTK;
  const float* bias = tpose ? biasV : biasK;
  unsigned short* dst = tpose ? dstV : dstK;
  const int tid = threadIdx.x;
  const int wid = tid >> 6, lane = tid & 63;
  const int q = lane & 15, g = lane >> 4;
  const int blockR0 = (bid & 511) * 64;        // 64 output rows per block
  const int R0 = blockR0 + wid * 16;
  const int row = R0 + q;
  const int bh = row >> 9, c = row & 511;
  const int b = bh >> 4, h = bh & 15;
  const float* sb = src + (((size_t)b * 2048 + (size_t)c * 4) * 16 + h) * 64;
  f32x4 acc[4];
  #pragma unroll
  for (int ct = 0; ct < 4; ++ct) acc[ct] = f32x4{0.f, 0.f, 0.f, 0.f};
  #pragma unroll
  for (int ch = 0; ch < 8; ++ch) {
    const int kk = ch * 32 + g * 8;
    const int w = kk >> 6, i = kk & 63;
    const float* s8 = sb + (size_t)w * 1024 + i;
    short8 a = cvt8(*(const f32x4*)s8, *(const f32x4*)(s8 + 4));
    #pragma unroll
    for (int ct = 0; ct < 4; ++ct) {
      short8 bf = *(const short8*)(kT + (ct * 16 + q) * 256 + ch * 32 + g * 8);
      acc[ct] = MFMA32(a, bf, acc[ct]);
    }
  }
  // epilogue: acc -> LDS (K: [c][dh], V: [dh][c]), barrier, coalesced stores
  #pragma unroll
  for (int ct = 0; ct < 4; ++ct) {
    const int col = ct * 16 + q;
    const float bv = bias[col];
    #pragma unroll
    for (int r = 0; r < 4; ++r) {
      const int lr = wid * 16 + 4 * g + r;     // local output row (c index)
      const unsigned short val = f2bf(acc[ct][r] + bv);
      t[tpose ? (col * 72 + lr) : (lr * 72 + col)] = val;
    }
  }
  __syncthreads();
  const int d = tid >> 2, sq = tid & 3;
  const short8 w0 = *(const short8*)(&t[d * 72 + sq * 16]);
  const short8 w1 = *(const short8*)(&t[d * 72 + sq * 16 + 8]);
  unsigned short* op;
  if (tpose) {
    const int bhb = blockR0 >> 9, cb = blockR0 & 511;
    op = dst + (size_t)bhb * 32768 + (size_t)d * 512 + cb + sq * 16;
  } else {
    op = dst + (size_t)(blockR0 + d) * 64 + sq * 16;
  }
  *(short8*)op = w0;
  *(short8*)(op + 8) = w1;
}

// ---------------------------------------------------------------------------
// 3) Attention v12/13 (measured 51-54us), unchanged.
__global__ __launch_bounds__(256) void attn_kernel(
    const float* __restrict__ preq, const unsigned int* __restrict__ mpk,
    const unsigned short* __restrict__ kc, const unsigned short* __restrict__ vt,
    unsigned short* __restrict__ merged) {
  __shared__ unsigned short shm[9728];   // Kl 2x(32*72)=4608 | Vl 2x(64*40)=5120
  unsigned short* Kl = shm;              // + buf*(32*72)
  unsigned short* Vl = shm + 4608;       // + buf*(64*40)
  const int tid = threadIdx.x;
  const int wid = tid >> 6, lane = tid & 63;
  const int q = lane & 15, g = lane >> 4;
  // XCD swizzle: bid&7 = XCD; per XCD one bp, 8 hp -> K/V/mask L2-resident.
  const int bid = blockIdx.x;
  const int x = bid & 7, ii = bid >> 3;              // ii in 0..127
  const int bp = x >> 1;
  const int hp = ((x & 1) << 3) | (ii & 7);
  const int tile = ii >> 3;                          // 16 tiles of 128 q-rows
  const int jj = hp * 4 + bp;
  const int bin = jj >> 4, hin = jj & 15;
  const int s0 = tile * 128 + wid * 32;

  const float QS = 0.18033688f;    // 0.125 * log2(e)
  const float* qpA = preq + (((size_t)bin * 2048 + s0 + q) * 16 + hin) * 64;
  const float* qpB = qpA + 16 * 1024;
  const short8 bqA0 = cvt8s(*(const f32x4*)(qpA + g * 8), *(const f32x4*)(qpA + g * 8 + 4), QS);
  const short8 bqA1 = cvt8s(*(const f32x4*)(qpA + 32 + g * 8), *(const f32x4*)(qpA + 32 + g * 8 + 4), QS);
  const short8 bqB0 = cvt8s(*(const f32x4*)(qpB + g * 8), *(const f32x4*)(qpB + g * 8 + 4), QS);
  const short8 bqB1 = cvt8s(*(const f32x4*)(qpB + 32 + g * 8), *(const f32x4*)(qpB + 32 + g * 8 + 4), QS);

  const unsigned short* kcb = kc + (size_t)jj * 512 * 64;
  const unsigned short* vtb = vt + (size_t)(bp * 16 + hp) * 64 * 512;
  const unsigned int* mrowA = mpk + ((size_t)bp * 2048 + s0 + q) * 16;
  const unsigned int* mrowB = mrowA + 256;

  // Staging roles: K chunk = 32 rows x 128B -> 8 threads/row x 16B;
  //                V chunk = 64 rows x 64B  -> 4 threads/row x 16B.
  const int krow = tid >> 3, kc8 = tid & 7;
  const unsigned short* gK = kcb + (size_t)krow * 64 + kc8 * 8;
  unsigned short* lK = Kl + krow * 72 + kc8 * 8;
  const int vrow = tid >> 2, vc4 = tid & 3;
  const unsigned short* gV = vtb + (size_t)vrow * 512 + vc4 * 8;
  unsigned short* lV = Vl + vrow * 40 + vc4 * 8;

  const short4v one4 = {(short)0x3F80, (short)0x3F80, (short)0x3F80, (short)0x3F80};

  f32x4 oA[4], oB[4];
  #pragma unroll
  for (int o = 0; o < 4; ++o) { oA[o] = f32x4{0,0,0,0}; oB[o] = f32x4{0,0,0,0}; }
  f32x4 oSA = {0,0,0,0}, oSB = {0,0,0,0};     // row-sum accumulators (ones-MFMA)

  // prologue: stage chunk 0 into buf 0; load chunk-0 mask words
  {
    const short8 sK = *(const short8*)gK;
    const short8 sV = *(const short8*)gV;
    *(short8*)lK = sK;
    *(short8*)lV = sV;
  }
  unsigned int mA = mrowA[0], mB = mrowB[0];
  __syncthreads();

  #pragma unroll 2
  for (int c = 0; c < 16; ++c) {
    // issue next chunk's staging loads + mask now (covered by this chunk)
    short8 nK, nV;
    unsigned int nmA = 0, nmB = 0;
    if (c < 15) {
      nK = *(const short8*)(gK + (size_t)(c + 1) * 2048);
      nV = *(const short8*)(gV + (c + 1) * 32);
      nmA = mrowA[c + 1];
      nmB = mrowB[c + 1];
    }
    const unsigned short* Kc_ = Kl + (c & 1) * (32 * 72);
    const unsigned short* Vc_ = Vl + (c & 1) * (64 * 40);
    // K frags (b128)
    const short8 ka0 = *(const short8*)(Kc_ + q * 72 + g * 8);
    const short8 ka1 = *(const short8*)(Kc_ + q * 72 + 32 + g * 8);
    const short8 kb0 = *(const short8*)(Kc_ + (16 + q) * 72 + g * 8);
    const short8 kb1 = *(const short8*)(Kc_ + (16 + q) * 72 + 32 + g * 8);
    // V frags for K=16 PV: keys sub*16 + 4g..+3 at dh row o*16+q
    short4v vf[4][2];
    #pragma unroll
    for (int o = 0; o < 4; ++o) {
      vf[o][0] = *(const short4v*)(Vc_ + (o * 16 + q) * 40 + g * 4);
      vf[o][1] = *(const short4v*)(Vc_ + (o * 16 + q) * 40 + 16 + g * 4);
    }
    __builtin_amdgcn_s_setprio(1);
    // QK^T (swapped): S^T[key][q]; acc reg r = key sub*16 + 4g + r, col q
    f32x4 s0A = {0,0,0,0}; s0A = MFMA32(ka0, bqA0, s0A); s0A = MFMA32(ka1, bqA1, s0A);
    f32x4 s1A = {0,0,0,0}; s1A = MFMA32(kb0, bqA0, s1A); s1A = MFMA32(kb1, bqA1, s1A);
    f32x4 s0B = {0,0,0,0}; s0B = MFMA32(ka0, bqB0, s0B); s0B = MFMA32(ka1, bqB1, s0B);
    f32x4 s1B = {0,0,0,0}; s1B = MFMA32(kb0, bqB0, s1B); s1B = MFMA32(kb1, bqB1, s1B);
    // P = mask ? exp2(S') : 0
    float pA[8], pB[8];
    #pragma unroll
    for (int r = 0; r < 4; ++r) {
      const int b0 = 4 * g + r, b1 = 16 + 4 * g + r;
      pA[r]     = ((mA >> b0) & 1u) ? __builtin_amdgcn_exp2f(s0A[r]) : 0.0f;
      pA[4 + r] = ((mA >> b1) & 1u) ? __builtin_amdgcn_exp2f(s1A[r]) : 0.0f;
      pB[r]     = ((mB >> b0) & 1u) ? __builtin_amdgcn_exp2f(s0B[r]) : 0.0f;
      pB[4 + r] = ((mB >> b1) & 1u) ? __builtin_amdgcn_exp2f(s1B[r]) : 0.0f;
    }
    // pack P to bf16 B-frags IN REGISTERS (C/D layout == K=16 B layout)
    const short4v pA0 = pk4(pA[0], pA[1], pA[2], pA[3]);
    const short4v pA1 = pk4(pA[4], pA[5], pA[6], pA[7]);
    const short4v pB0 = pk4(pB[0], pB[1], pB[2], pB[3]);
    const short4v pB1 = pk4(pB[4], pB[5], pB[6], pB[7]);
    // PV: O^T[dh][q] += V^T . P^T via K=16 MFMAs; row-sums via ones-MFMA
    #pragma unroll
    for (int o = 0; o < 4; ++o) {
      oA[o] = MFMA16(vf[o][0], pA0, oA[o]);
      oA[o] = MFMA16(vf[o][1], pA1, oA[o]);
      oB[o] = MFMA16(vf[o][0], pB0, oB[o]);
      oB[o] = MFMA16(vf[o][1], pB1, oB[o]);
    }
    oSA = MFMA16(one4, pA0, oSA); oSA = MFMA16(one4, pA1, oSA);
    oSB = MFMA16(one4, pB0, oSB); oSB = MFMA16(one4, pB1, oSB);
    __builtin_amdgcn_s_setprio(0);
    // stage chunk c+1 into the opposite buffer
    if (c < 15) {
      *(short8*)(lK + ((c + 1) & 1) * (32 * 72)) = nK;
      *(short8*)(lV + ((c + 1) & 1) * (64 * 40)) = nV;
    }
    __syncthreads();                 // one barrier/chunk
    mA = nmA; mB = nmB;
  }

  const float rlA = 1.0f / oSA[0], rlB = 1.0f / oSB[0];

  // Epilogue (stride-72 rows -> bank varies with q, no 16-way conflicts):
  // O^T regs -> LDS -> coalesced bf16 stores. Reuses shm after final barrier.
  unsigned short* eb = shm + wid * 2304;           // per-wave 2 qsets x 16 x 72
  #pragma unroll
  for (int qs = 0; qs < 2; ++qs) {
    unsigned int* U = (unsigned int*)(eb + qs * 1152);
    const float rl = qs ? rlB : rlA;
    #pragma unroll
    for (int o = 0; o < 4; ++o) {
      const f32x4 ov = qs ? oB[o] : oA[o];
      U[q * 36 + o * 8 + 2 * g]     = pack2c(ov[0] * rl, ov[1] * rl);
      U[q * 36 + o * 8 + 2 * g + 1] = pack2c(ov[2] * rl, ov[3] * rl);
    }
  }
  const int ir = lane >> 2, sg2 = lane & 3;
  #pragma unroll
  for (int qs = 0; qs < 2; ++qs) {
    const unsigned short* ep = eb + qs * 1152;
    const short8 w0 = *(const short8*)(ep + ir * 72 + sg2 * 16);
    const short8 w1 = *(const short8*)(ep + ir * 72 + sg2 * 16 + 8);
    unsigned short* mp = merged + ((size_t)(bp * 2048 + s0 + qs * 16 + ir)) * 1024 + hp * 64 + sg2 * 16;
    *(short8*)mp = w0;
    *(short8*)(mp + 8) = w1;
  }
}

// ---------------------------------------------------------------------------
// 4) Output projection, distance-2 pipeline: 4 LDS buffers, prefetch k-steps
// t+2/t+3 at the top of each 2-step iteration, ONE barrier per 2 k-steps
// (was 1/step). Prefetch cover doubles (~300cyc >= L2 latency); barrier
// drains halve. A-frags register-prefetched 2 steps ahead.
__global__ __launch_bounds__(256) void gemm_kernel(
    const unsigned short* __restrict__ A, const unsigned short* __restrict__ BT,
    float* __restrict__ out) {
  __shared__ unsigned short Bb[4][4096];   // 4 x 8KB k-step buffers, XOR-swizzled
  const int tid = threadIdx.x;
  const int wid = tid >> 6, lane = tid & 63;
  const int q = lane & 15, g = lane >> 4;
  const int bid = blockIdx.x;
  const int x = bid & 7, i = bid >> 3;
  const int N0 = (i & 7) * 128;
  const int M0 = (x * 8 + (i >> 3)) * 128 + wid * 32;

  const int r0 = wid * 32 + (lane >> 2);
  const int r1 = r0 + 16;
  const int sc = (lane & 3) * 16;
  const int b0 = sc ^ (((r0 >> 2) & 3) << 4);
  const int b1 = sc ^ (((r1 >> 2) & 3) << 4);
  const unsigned short* gs0 = BT + (size_t)(N0 + r0) * 1024 + (b0 >> 1);
  const unsigned short* gs1 = BT + (size_t)(N0 + r1) * 1024 + (b1 >> 1);
  const int bsz = ((q >> 2) & 3) << 4;

  f32x4 acc[2][8];
  #pragma unroll
  for (int rt = 0; rt < 2; ++rt)
    #pragma unroll
    for (int ct = 0; ct < 8; ++ct) acc[rt][ct] = f32x4{0.f, 0.f, 0.f, 0.f};
  const unsigned short* a0p = A + (size_t)(M0 + q) * 1024 + g * 8;
  const unsigned short* a1p = a0p + 16 * 1024;

  // prologue: stage k-steps 0 and 1; A-frags for steps 0,1
  gl_lds16(gs0,      &Bb[0][wid * 1024]);
  gl_lds16(gs1,      &Bb[0][wid * 1024 + 512]);
  gl_lds16(gs0 + 32, &Bb[1][wid * 1024]);
  gl_lds16(gs1 + 32, &Bb[1][wid * 1024 + 512]);
  short8 aC00 = *(const short8*)(a0p);
  short8 aC01 = *(const short8*)(a1p);
  short8 aC10 = *(const short8*)(a0p + 32);
  short8 aC11 = *(const short8*)(a1p + 32);
  __syncthreads();

  for (int t = 0; t < 32; t += 2) {
    if (t < 30) {                  // prefetch k-steps t+2, t+3
      gl_lds16(gs0 + (t + 2) * 32, &Bb[(t + 2) & 3][wid * 1024]);
      gl_lds16(gs1 + (t + 2) * 32, &Bb[(t + 2) & 3][wid * 1024 + 512]);
      gl_lds16(gs0 + (t + 3) * 32, &Bb[(t + 3) & 3][wid * 1024]);
      gl_lds16(gs1 + (t + 3) * 32, &Bb[(t + 3) & 3][wid * 1024 + 512]);
    }
    short8 aN00 = aC00, aN01 = aC01, aN10 = aC10, aN11 = aC11;
    if (t < 30) {
      aN00 = *(const short8*)(a0p + (t + 2) * 32);
      aN01 = *(const short8*)(a1p + (t + 2) * 32);
      aN10 = *(const short8*)(a0p + (t + 3) * 32);
      aN11 = *(const short8*)(a1p + (t + 3) * 32);
    }
    const unsigned short* Bc0 = &Bb[t & 3][0];
    const unsigned short* Bc1 = &Bb[(t + 1) & 3][0];
    #pragma unroll
    for (int ct = 0; ct < 8; ++ct) {
      const int off = (ct * 16 + q) * 32 + (((g * 16) ^ bsz) >> 1);
      const short8 bfr0 = *(const short8*)(Bc0 + off);
      acc[0][ct] = MFMA32(aC00, bfr0, acc[0][ct]);
      acc[1][ct] = MFMA32(aC01, bfr0, acc[1][ct]);
      const short8 bfr1 = *(const short8*)(Bc1 + off);
      acc[0][ct] = MFMA32(aC10, bfr1, acc[0][ct]);
      acc[1][ct] = MFMA32(aC11, bfr1, acc[1][ct]);
    }
    aC00 = aN00; aC01 = aN01; aC10 = aN10; aC11 = aN11;
    __syncthreads();               // one barrier per 2 k-steps
  }
  #pragma unroll
  for (int rt = 0; rt < 2; ++rt)
    #pragma unroll
    for (int ct = 0; ct < 8; ++ct)
      #pragma unroll
      for (int r = 0; r < 4; ++r)
        out[(size_t)(M0 + rt * 16 + 4 * g + r) * 1024 + N0 + ct * 16 + q] = acc[rt][ct][r];
}

// ---------------------------------------------------------------------------
extern "C" void kernel_launch(void* const* d_in, const int* in_sizes, int n_in,
                              void* d_out, int out_size, void* d_ws, size_t ws_size,
                              hipStream_t stream) {
  const float* preq = (const float*)d_in[0];
  const float* prev = (const float*)d_in[1];
  const float* prek = (const float*)d_in[2];
  const float* W    = (const float*)d_in[3];
  const float* kck  = (const float*)d_in[4];
  const float* kcb  = (const float*)d_in[5];
  const float* vck  = (const float*)d_in[6];
  const float* vcb  = (const float*)d_in[7];
  const int*   msk  = (const int*)d_in[8];
  float* out = (float*)d_out;

  char* ws = (char*)d_ws;
  unsigned short* WT  = (unsigned short*)(ws);                      // 2 MB
  unsigned short* kkT = (unsigned short*)(ws + 2097152);            // 64 KB
  unsigned short* vkT = (unsigned short*)(ws + 2129920);            // 64 KB
  unsigned short* kcB = (unsigned short*)(ws + 2162688);            // 4 MB  [bh][c][dh]
  unsigned short* vcT = (unsigned short*)(ws + 6356992);            // 4 MB  [bh][dh][c]
  unsigned short* mrg = (unsigned short*)(ws + 10551296);           // 16 MB [8192][1024]
  unsigned int*   mpk = (unsigned int*)(ws + 27328512);             // 512 KB packed mask

  hipLaunchKernelGGL(prep_kernel, dim3(896), dim3(256), 0, stream,
                     W, WT, kck, kkT, vck, vkT, msk, mpk);
  hipLaunchKernelGGL(compress_kernel, dim3(1024), dim3(256), 0, stream,
                     prek, kkT, kcb, kcB, prev, vkT, vcb, vcT);
  hipLaunchKernelGGL(attn_kernel, dim3(1024), dim3(256), 0, stream, preq, mpk, kcB, vcT, mrg);
  hipLaunchKernelGGL(gemm_kernel, dim3(512), dim3(256), 0, stream, mrg, WT, out);
}

// Round 15
// 91.258 us; speedup vs baseline: 1.5431x; 1.1621x over previous
//
#include <hip/hip_runtime.h>
#include <hip/hip_bf16.h>

// Problem constants (fixed by setup_inputs): B=4, S=2048, H=16, DH=64, W=4,
// Kc=512, D=1024. Output (4,2048,1024) f32.

typedef __attribute__((ext_vector_type(8))) short short8;   // 8 bf16 (4 VGPRs)
typedef __attribute__((ext_vector_type(4))) short short4v;  // 4 bf16 (2 VGPRs)
typedef __attribute__((ext_vector_type(4))) float f32x4;
typedef __attribute__((ext_vector_type(4))) int int4e;
typedef __attribute__((ext_vector_type(2))) unsigned int u32x2;

#define MFMA32(A, Bf, C) __builtin_amdgcn_mfma_f32_16x16x32_bf16((A), (Bf), (C), 0, 0, 0)
#define MFMA16(A, Bf, C) __builtin_amdgcn_mfma_f32_16x16x16bf16_1k((A), (Bf), (C), 0, 0, 0)

static __device__ __forceinline__ unsigned short f2bf(float f) {
  unsigned int u = __builtin_bit_cast(unsigned int, f);
  u += 0x7fffu + ((u >> 16) & 1u);   // RNE (finite inputs only)
  return (unsigned short)(u >> 16);
}
static __device__ __forceinline__ unsigned int pack2c(float a, float b) {
  unsigned short lo = __builtin_bit_cast(unsigned short, __float2bfloat16(a));
  unsigned short hi = __builtin_bit_cast(unsigned short, __float2bfloat16(b));
  return (unsigned int)lo | ((unsigned int)hi << 16);
}
// 4x f32 -> 4x bf16 via packed-pair conversions (v_cvt_pk_bf16_f32)
static __device__ __forceinline__ short4v pk4(float a, float b, float c, float d) {
  u32x2 t;
  t[0] = pack2c(a, b);
  t[1] = pack2c(c, d);
  return __builtin_bit_cast(short4v, t);
}
static __device__ __forceinline__ short8 cvt8(f32x4 lo, f32x4 hi) {
  short8 r;
  r[0] = (short)f2bf(lo[0]); r[1] = (short)f2bf(lo[1]);
  r[2] = (short)f2bf(lo[2]); r[3] = (short)f2bf(lo[3]);
  r[4] = (short)f2bf(hi[0]); r[5] = (short)f2bf(hi[1]);
  r[6] = (short)f2bf(hi[2]); r[7] = (short)f2bf(hi[3]);
  return r;
}
static __device__ __forceinline__ short8 cvt8s(f32x4 lo, f32x4 hi, float s) {
  short8 r;
  r[0] = (short)f2bf(lo[0]*s); r[1] = (short)f2bf(lo[1]*s);
  r[2] = (short)f2bf(lo[2]*s); r[3] = (short)f2bf(lo[3]*s);
  r[4] = (short)f2bf(hi[0]*s); r[5] = (short)f2bf(hi[1]*s);
  r[6] = (short)f2bf(hi[2]*s); r[7] = (short)f2bf(hi[3]*s);
  return r;
}
// async global -> LDS, 16B/lane (used only in gemm, where it measured faster)
static __device__ __forceinline__ void gl_lds16(const void* g, void* l) {
  __builtin_amdgcn_global_load_lds(
      (const __attribute__((address_space(1))) unsigned int*)g,
      (__attribute__((address_space(3))) unsigned int*)l, 16, 0, 0);
}

// ---------------------------------------------------------------------------
// 1) Fused pre: [0,1024) conv1d compression (self-transposes the conv kernel
// into padded LDS — no dependency on a prep pass); [1024,1280) transpose W;
// [1280,1792) pack mask bits. One launch replaces prep+compress.
__global__ __launch_bounds__(256) void pre_kernel(
    const float* __restrict__ srcK, const float* __restrict__ kckRaw,
    const float* __restrict__ biasK, unsigned short* __restrict__ dstK,
    const float* __restrict__ srcV, const float* __restrict__ vckRaw,
    const float* __restrict__ biasV, unsigned short* __restrict__ dstV,
    const float* __restrict__ W, unsigned short* __restrict__ WT,
    const int* __restrict__ msk, unsigned int* __restrict__ mpk) {
  __shared__ unsigned short shm[21504];          // 43008 B
  const int bid = blockIdx.x;
  const int tid = threadIdx.x;
  if (bid < 1024) {
    // ---- compress as MFMA GEMM ----
    const int tpose = bid >> 9;
    const float* src = tpose ? srcV : srcK;
    const float* kraw = tpose ? vckRaw : kckRaw;
    const float* bias = tpose ? biasV : biasK;
    unsigned short* dst = tpose ? dstV : dstK;
    unsigned short* kTl = shm;                   // [o=64][kk=256 pad 264]
    unsigned short* t = shm + 16896;             // [64][72] epilogue tile
    // fill kTl from raw (4,64,64) f32 = flat [kk][o]; coalesced 256B reads,
    // b128 LDS writes (structural-minimum phases), 4-bank-stepped reads.
    {
      const int o = tid & 63, m0 = tid >> 6;
      #pragma unroll
      for (int it = 0; it < 8; ++it) {
        const int kk0 = (it * 4 + m0) * 8;
        short8 v;
        #pragma unroll
        for (int s = 0; s < 8; ++s)
          v[s] = (short)f2bf(kraw[(size_t)(kk0 + s) * 64 + o]);
        *(short8*)(kTl + o * 264 + kk0) = v;
      }
    }
    __syncthreads();
    const int wid = tid >> 6, lane = tid & 63;
    const int q = lane & 15, g = lane >> 4;
    const int blockR0 = (bid & 511) * 64;
    const int R0 = blockR0 + wid * 16;
    const int row = R0 + q;
    const int bh = row >> 9, c = row & 511;
    const int b = bh >> 4, h = bh & 15;
    const float* sb = src + (((size_t)b * 2048 + (size_t)c * 4) * 16 + h) * 64;
    f32x4 acc[4];
    #pragma unroll
    for (int ct = 0; ct < 4; ++ct) acc[ct] = f32x4{0.f, 0.f, 0.f, 0.f};
    #pragma unroll
    for (int ch = 0; ch < 8; ++ch) {
      const int kk = ch * 32 + g * 8;
      const int w = kk >> 6, i = kk & 63;
      const float* s8 = sb + (size_t)w * 1024 + i;
      short8 a = cvt8(*(const f32x4*)s8, *(const f32x4*)(s8 + 4));
      #pragma unroll
      for (int ct = 0; ct < 4; ++ct) {
        short8 bf = *(const short8*)(kTl + (ct * 16 + q) * 264 + ch * 32 + g * 8);
        acc[ct] = MFMA32(a, bf, acc[ct]);
      }
    }
    // epilogue: acc -> LDS (K: [c][dh], V: [dh][c]), barrier, coalesced stores
    #pragma unroll
    for (int ct = 0; ct < 4; ++ct) {
      const int col = ct * 16 + q;
      const float bv = bias[col];
      #pragma unroll
      for (int r = 0; r < 4; ++r) {
        const int lr = wid * 16 + 4 * g + r;
        const unsigned short val = f2bf(acc[ct][r] + bv);
        t[tpose ? (col * 72 + lr) : (lr * 72 + col)] = val;
      }
    }
    __syncthreads();
    const int d = tid >> 2, sq = tid & 3;
    const short8 w0 = *(const short8*)(&t[d * 72 + sq * 16]);
    const short8 w1 = *(const short8*)(&t[d * 72 + sq * 16 + 8]);
    unsigned short* op;
    if (tpose) {
      const int bhb = blockR0 >> 9, cb = blockR0 & 511;
      op = dst + (size_t)bhb * 32768 + (size_t)d * 512 + cb + sq * 16;
    } else {
      op = dst + (size_t)(blockR0 + d) * 64 + sq * 16;
    }
    *(short8*)op = w0;
    *(short8*)(op + 8) = w1;
  } else if (bid < 1280) {
    // ---- W (1024x1024 f32 [k][n]) -> WT bf16 [n][k], LDS-tiled ----
    unsigned short (*t2)[72] = (unsigned short (*)[72])shm;
    const int wb = bid - 1024;
    const int k0 = (wb & 15) * 64, n0 = (wb >> 4) * 64;
    const int cr = tid >> 4, cc = (tid & 15) * 4;
    #pragma unroll
    for (int it = 0; it < 4; ++it) {
      const int kk = it * 16 + cr;
      const f32x4 v = *(const f32x4*)(W + (size_t)(k0 + kk) * 1024 + n0 + cc);
      #pragma unroll
      for (int j = 0; j < 4; ++j) t2[cc + j][kk] = f2bf(v[j]);
    }
    __syncthreads();
    const int rn = tid >> 2, seg = tid & 3;
    const short8 w0 = *(const short8*)(&t2[rn][seg * 16]);
    const short8 w1 = *(const short8*)(&t2[rn][seg * 16 + 8]);
    unsigned short* op = WT + (size_t)(n0 + rn) * 1024 + k0 + seg * 16;
    *(short8*)op = w0;
    *(short8*)(op + 8) = w1;
  } else {
    // ---- mask int32 -> bit-packed u32 ----
    const int w = (bid - 1280) * 256 + tid;
    const int* p = msk + (size_t)w * 32;
    unsigned int b = 0;
    #pragma unroll
    for (int i = 0; i < 8; ++i) {
      const int4e v = *(const int4e*)(p + i * 4);
      b |= (unsigned int)(v[0] & 1) << (i * 4);
      b |= (unsigned int)(v[1] & 1) << (i * 4 + 1);
      b |= (unsigned int)(v[2] & 1) << (i * 4 + 2);
      b |= (unsigned int)(v[3] & 1) << (i * 4 + 3);
    }
    mpk[w] = b;
  }
}

// ---------------------------------------------------------------------------
// 3) Attention v15: 64-key superchunks (8 barriers vs 16), K AND V both
// reg-staged into double-buffered LDS (V-from-global was R11's proven
// mistake — kept in LDS here). P never leaves registers (K=16 PV),
// ones-MFMA row-sums, stride-72/144 padded layouts (2-way = free).
__global__ __launch_bounds__(256) void attn_kernel(
    const float* __restrict__ preq, const unsigned int* __restrict__ mpk,
    const unsigned short* __restrict__ kc, const unsigned short* __restrict__ vt,
    unsigned short* __restrict__ merged) {
  __shared__ unsigned short shm[18432];   // 36864 B: K 2x4608sh | V 2x4608sh
  unsigned short* Kl = shm;               // + buf*4608 (64 keys x 72)
  unsigned short* Vl = shm + 9216;        // + buf*4608 (64 dh x 72)
  const int tid = threadIdx.x;
  const int wid = tid >> 6, lane = tid & 63;
  const int q = lane & 15, g = lane >> 4;
  // XCD swizzle: bid&7 = XCD; per XCD one bp, 8 hp -> K/V/mask L2-resident.
  const int bid = blockIdx.x;
  const int x = bid & 7, ii = bid >> 3;              // ii in 0..127
  const int bp = x >> 1;
  const int hp = ((x & 1) << 3) | (ii & 7);
  const int tile = ii >> 3;                          // 16 tiles of 128 q-rows
  const int jj = hp * 4 + bp;
  const int bin = jj >> 4, hin = jj & 15;
  const int s0 = tile * 128 + wid * 32;

  const float QS = 0.18033688f;    // 0.125 * log2(e)
  const float* qpA = preq + (((size_t)bin * 2048 + s0 + q) * 16 + hin) * 64;
  const float* qpB = qpA + 16 * 1024;
  const short8 bqA0 = cvt8s(*(const f32x4*)(qpA + g * 8), *(const f32x4*)(qpA + g * 8 + 4), QS);
  const short8 bqA1 = cvt8s(*(const f32x4*)(qpA + 32 + g * 8), *(const f32x4*)(qpA + 32 + g * 8 + 4), QS);
  const short8 bqB0 = cvt8s(*(const f32x4*)(qpB + g * 8), *(const f32x4*)(qpB + g * 8 + 4), QS);
  const short8 bqB1 = cvt8s(*(const f32x4*)(qpB + 32 + g * 8), *(const f32x4*)(qpB + 32 + g * 8 + 4), QS);

  const unsigned short* kcb = kc + (size_t)jj * 512 * 64;
  const unsigned short* vtb = vt + (size_t)(bp * 16 + hp) * 64 * 512;
  const unsigned int* mrowA = mpk + ((size_t)bp * 2048 + s0 + q) * 16;
  const unsigned int* mrowB = mrowA + 256;

  // Staging: K superchunk = 64 keys x 128B; V superchunk = 64 dh x 128B.
  // Each thread: 2 x 16B for K (rows sr, sr+32), 2 x 16B for V.
  const int sr = tid >> 3, sseg = tid & 7;
  const unsigned short* gK0 = kcb + (size_t)sr * 64 + sseg * 8;
  const unsigned short* gK1 = gK0 + 32 * 64;
  unsigned short* lK0 = Kl + sr * 72 + sseg * 8;
  unsigned short* lK1 = lK0 + 32 * 72;
  const unsigned short* gV0 = vtb + (size_t)sr * 512 + sseg * 8;
  const unsigned short* gV1 = gV0 + 32 * 512;
  unsigned short* lV0 = Vl + sr * 72 + sseg * 8;
  unsigned short* lV1 = lV0 + 32 * 72;

  const short4v one4 = {(short)0x3F80, (short)0x3F80, (short)0x3F80, (short)0x3F80};

  f32x4 oA[4], oB[4];
  #pragma unroll
  for (int o = 0; o < 4; ++o) { oA[o] = f32x4{0,0,0,0}; oB[o] = f32x4{0,0,0,0}; }
  f32x4 oSA = {0,0,0,0}, oSB = {0,0,0,0};     // row-sum accumulators (ones-MFMA)

  // prologue: stage superchunk 0 into buf 0; load its mask words
  *(short8*)lK0 = *(const short8*)gK0;
  *(short8*)lK1 = *(const short8*)gK1;
  *(short8*)lV0 = *(const short8*)gV0;
  *(short8*)lV1 = *(const short8*)gV1;
  u32x2 mA2 = *(const u32x2*)mrowA;
  u32x2 mB2 = *(const u32x2*)mrowB;
  __syncthreads();

  #pragma unroll 2
  for (int sc = 0; sc < 8; ++sc) {
    // prefetch next superchunk (K, V, mask) into rotation regs
    short8 nK0, nK1, nV0, nV1;
    u32x2 nmA = {0, 0}, nmB = {0, 0};
    if (sc < 7) {
      nK0 = *(const short8*)(gK0 + (size_t)(sc + 1) * 4096);
      nK1 = *(const short8*)(gK1 + (size_t)(sc + 1) * 4096);
      nV0 = *(const short8*)(gV0 + (sc + 1) * 64);
      nV1 = *(const short8*)(gV1 + (sc + 1) * 64);
      nmA = *(const u32x2*)(mrowA + 2 * (sc + 1));
      nmB = *(const u32x2*)(mrowB + 2 * (sc + 1));
    }
    const unsigned short* Kc_ = Kl + (sc & 1) * 4608;
    const unsigned short* Vc_ = Vl + (sc & 1) * 4608;
    __builtin_amdgcn_s_setprio(1);
    // QK^T (swapped) over 4 sub-blocks of 16 keys; P stays in registers
    short4v pA[4], pB[4];
    #pragma unroll
    for (int sub = 0; sub < 4; ++sub) {
      const short8 k0 = *(const short8*)(Kc_ + (sub * 16 + q) * 72 + g * 8);
      const short8 k1 = *(const short8*)(Kc_ + (sub * 16 + q) * 72 + 32 + g * 8);
      f32x4 sA = {0,0,0,0}; sA = MFMA32(k0, bqA0, sA); sA = MFMA32(k1, bqA1, sA);
      f32x4 sB = {0,0,0,0}; sB = MFMA32(k0, bqB0, sB); sB = MFMA32(k1, bqB1, sB);
      const unsigned int wA = mA2[sub >> 1], wB = mB2[sub >> 1];
      const int bb = (sub & 1) * 16 + 4 * g;
      float eA[4], eB[4];
      #pragma unroll
      for (int r = 0; r < 4; ++r) {
        eA[r] = ((wA >> (bb + r)) & 1u) ? __builtin_amdgcn_exp2f(sA[r]) : 0.0f;
        eB[r] = ((wB >> (bb + r)) & 1u) ? __builtin_amdgcn_exp2f(sB[r]) : 0.0f;
      }
      pA[sub] = pk4(eA[0], eA[1], eA[2], eA[3]);
      pB[sub] = pk4(eB[0], eB[1], eB[2], eB[3]);
    }
    // PV: O^T[dh][q] += V^T . P^T via K=16 MFMAs (V frags from LDS);
    // ones-MFMA row-sums
    #pragma unroll
    for (int o = 0; o < 4; ++o) {
      #pragma unroll
      for (int sub = 0; sub < 4; ++sub) {
        const short4v vfr = *(const short4v*)(Vc_ + (o * 16 + q) * 72 + sub * 16 + g * 4);
        oA[o] = MFMA16(vfr, pA[sub], oA[o]);
        oB[o] = MFMA16(vfr, pB[sub], oB[o]);
      }
    }
    #pragma unroll
    for (int sub = 0; sub < 4; ++sub) {
      oSA = MFMA16(one4, pA[sub], oSA);
      oSB = MFMA16(one4, pB[sub], oSB);
    }
    __builtin_amdgcn_s_setprio(0);
    // stage next superchunk into the opposite buffer
    if (sc < 7) {
      const int nb = ((sc + 1) & 1) * 4608;
      *(short8*)(lK0 + nb) = nK0;
      *(short8*)(lK1 + nb) = nK1;
      *(short8*)(lV0 + nb) = nV0;
      *(short8*)(lV1 + nb) = nV1;
    }
    __syncthreads();                 // ONE barrier per 64 keys
    mA2 = nmA; mB2 = nmB;
  }

  const float rlA = 1.0f / oSA[0], rlB = 1.0f / oSB[0];

  // Epilogue (stride-72 rows -> bank varies with q): O^T regs -> LDS ->
  // coalesced bf16 stores. Reuses shm after the final barrier.
  unsigned short* eb = shm + wid * 2304;           // per-wave 2 qsets x 16 x 72
  #pragma unroll
  for (int qs = 0; qs < 2; ++qs) {
    unsigned int* U = (unsigned int*)(eb + qs * 1152);
    const float rl = qs ? rlB : rlA;
    #pragma unroll
    for (int o = 0; o < 4; ++o) {
      const f32x4 ov = qs ? oB[o] : oA[o];
      U[q * 36 + o * 8 + 2 * g]     = pack2c(ov[0] * rl, ov[1] * rl);
      U[q * 36 + o * 8 + 2 * g + 1] = pack2c(ov[2] * rl, ov[3] * rl);
    }
  }
  const int ir = lane >> 2, sg2 = lane & 3;
  #pragma unroll
  for (int qs = 0; qs < 2; ++qs) {
    const unsigned short* ep = eb + qs * 1152;
    const short8 w0 = *(const short8*)(ep + ir * 72 + sg2 * 16);
    const short8 w1 = *(const short8*)(ep + ir * 72 + sg2 * 16 + 8);
    unsigned short* mp = merged + ((size_t)(bp * 2048 + s0 + qs * 16 + ir)) * 1024 + hp * 64 + sg2 * 16;
    *(short8*)mp = w0;
    *(short8*)(mp + 8) = w1;
  }
}

// ---------------------------------------------------------------------------
// 4) Output projection, distance-2 pipeline (R14, measured slightly faster).
__global__ __launch_bounds__(256) void gemm_kernel(
    const unsigned short* __restrict__ A, const unsigned short* __restrict__ BT,
    float* __restrict__ out) {
  __shared__ unsigned short Bb[4][4096];   // 4 x 8KB k-step buffers, XOR-swizzled
  const int tid = threadIdx.x;
  const int wid = tid >> 6, lane = tid & 63;
  const int q = lane & 15, g = lane >> 4;
  const int bid = blockIdx.x;
  const int x = bid & 7, i = bid >> 3;
  const int N0 = (i & 7) * 128;
  const int M0 = (x * 8 + (i >> 3)) * 128 + wid * 32;

  const int r0 = wid * 32 + (lane >> 2);
  const int r1 = r0 + 16;
  const int sc = (lane & 3) * 16;
  const int b0 = sc ^ (((r0 >> 2) & 3) << 4);
  const int b1 = sc ^ (((r1 >> 2) & 3) << 4);
  const unsigned short* gs0 = BT + (size_t)(N0 + r0) * 1024 + (b0 >> 1);
  const unsigned short* gs1 = BT + (size_t)(N0 + r1) * 1024 + (b1 >> 1);
  const int bsz = ((q >> 2) & 3) << 4;

  f32x4 acc[2][8];
  #pragma unroll
  for (int rt = 0; rt < 2; ++rt)
    #pragma unroll
    for (int ct = 0; ct < 8; ++ct) acc[rt][ct] = f32x4{0.f, 0.f, 0.f, 0.f};
  const unsigned short* a0p = A + (size_t)(M0 + q) * 1024 + g * 8;
  const unsigned short* a1p = a0p + 16 * 1024;

  gl_lds16(gs0,      &Bb[0][wid * 1024]);
  gl_lds16(gs1,      &Bb[0][wid * 1024 + 512]);
  gl_lds16(gs0 + 32, &Bb[1][wid * 1024]);
  gl_lds16(gs1 + 32, &Bb[1][wid * 1024 + 512]);
  short8 aC00 = *(const short8*)(a0p);
  short8 aC01 = *(const short8*)(a1p);
  short8 aC10 = *(const short8*)(a0p + 32);
  short8 aC11 = *(const short8*)(a1p + 32);
  __syncthreads();

  for (int t = 0; t < 32; t += 2) {
    if (t < 30) {
      gl_lds16(gs0 + (t + 2) * 32, &Bb[(t + 2) & 3][wid * 1024]);
      gl_lds16(gs1 + (t + 2) * 32, &Bb[(t + 2) & 3][wid * 1024 + 512]);
      gl_lds16(gs0 + (t + 3) * 32, &Bb[(t + 3) & 3][wid * 1024]);
      gl_lds16(gs1 + (t + 3) * 32, &Bb[(t + 3) & 3][wid * 1024 + 512]);
    }
    short8 aN00 = aC00, aN01 = aC01, aN10 = aC10, aN11 = aC11;
    if (t < 30) {
      aN00 = *(const short8*)(a0p + (t + 2) * 32);
      aN01 = *(const short8*)(a1p + (t + 2) * 32);
      aN10 = *(const short8*)(a0p + (t + 3) * 32);
      aN11 = *(const short8*)(a1p + (t + 3) * 32);
    }
    const unsigned short* Bc0 = &Bb[t & 3][0];
    const unsigned short* Bc1 = &Bb[(t + 1) & 3][0];
    #pragma unroll
    for (int ct = 0; ct < 8; ++ct) {
      const int off = (ct * 16 + q) * 32 + (((g * 16) ^ bsz) >> 1);
      const short8 bfr0 = *(const short8*)(Bc0 + off);
      acc[0][ct] = MFMA32(aC00, bfr0, acc[0][ct]);
      acc[1][ct] = MFMA32(aC01, bfr0, acc[1][ct]);
      const short8 bfr1 = *(const short8*)(Bc1 + off);
      acc[0][ct] = MFMA32(aC10, bfr1, acc[0][ct]);
      acc[1][ct] = MFMA32(aC11, bfr1, acc[1][ct]);
    }
    aC00 = aN00; aC01 = aN01; aC10 = aN10; aC11 = aN11;
    __syncthreads();
  }
  #pragma unroll
  for (int rt = 0; rt < 2; ++rt)
    #pragma unroll
    for (int ct = 0; ct < 8; ++ct)
      #pragma unroll
      for (int r = 0; r < 4; ++r)
        out[(size_t)(M0 + rt * 16 + 4 * g + r) * 1024 + N0 + ct * 16 + q] = acc[rt][ct][r];
}

// ---------------------------------------------------------------------------
extern "C" void kernel_launch(void* const* d_in, const int* in_sizes, int n_in,
                              void* d_out, int out_size, void* d_ws, size_t ws_size,
                              hipStream_t stream) {
  const float* preq = (const float*)d_in[0];
  const float* prev = (const float*)d_in[1];
  const float* prek = (const float*)d_in[2];
  const float* W    = (const float*)d_in[3];
  const float* kck  = (const float*)d_in[4];
  const float* kcb  = (const float*)d_in[5];
  const float* vck  = (const float*)d_in[6];
  const float* vcb  = (const float*)d_in[7];
  const int*   msk  = (const int*)d_in[8];
  float* out = (float*)d_out;

  char* ws = (char*)d_ws;
  unsigned short* WT  = (unsigned short*)(ws);                      // 2 MB
  unsigned short* kcB = (unsigned short*)(ws + 2162688);            // 4 MB  [bh][c][dh]
  unsigned short* vcT = (unsigned short*)(ws + 6356992);            // 4 MB  [bh][dh][c]
  unsigned short* mrg = (unsigned short*)(ws + 10551296);           // 16 MB [8192][1024]
  unsigned int*   mpk = (unsigned int*)(ws + 27328512);             // 512 KB packed mask

  hipLaunchKernelGGL(pre_kernel, dim3(1792), dim3(256), 0, stream,
                     prek, kck, kcb, kcB, prev, vck, vcb, vcT, W, WT, msk, mpk);
  hipLaunchKernelGGL(attn_kernel, dim3(1024), dim3(256), 0, stream, preq, mpk, kcB, vcT, mrg);
  hipLaunchKernelGGL(gemm_kernel, dim3(512), dim3(256), 0, stream, mrg, WT, out);
}